// Round 4
// baseline (531.763 us; speedup 1.0000x reference)
//
#include <hip/hip_runtime.h>
#include <cstdint>
#include <cstddef>

// ---------------------------------------------------------------------------
// DynamicMemoryCell on MI355X (gfx950) — round 8
//
// Math: softmax over 1 key == 1 -> attn == v; q/k/pm dead.
// Linear chain pi->v->ctx->gi collapsed: Wcomb = Wih@Wop@Wv@Wip (per call).
//
// Round-8 vs round-7: the round-7 post-mortem showed MfmaUtil pinned at 20%
// == MFMA-phase(~78cyc) / load-latency(~400cyc): the 2-buffer pipeline waits
// vmcnt(0) on loads issued in the SAME K-step. Fix = pipeline depth 2:
//   * TRIPLE-buffered BK=32 LDS (48 KiB): step kt reads buf0, buf1 has
//     tile kt+1 in flight (issued at kt-1), issue tile kt+2 into buf2;
//     end-of-step s_waitcnt vmcnt(LPS) — tile kt+1 landed, tile kt+2's
//     loads STAY IN FLIGHT across the barrier (counted vmcnt, T4; never
//     drains to 0 in the loop).  LPS = loads/stage = BM/64 + 2.
//   * latency budget per load batch: ~1.5 K-steps (~500+ cyc) vs ~0.3.
//   * 2-way-minimal XOR swizzle kept (round-7: bank conflicts 6.29M -> 0).
//   * tail: last tile re-staged redundantly (uniform vmcnt accounting);
//     vmcnt(0) after loop before epilogue/exit.
// ---------------------------------------------------------------------------

typedef __bf16 bf16;
typedef bf16 bf16x4 __attribute__((ext_vector_type(4)));
typedef bf16 bf16x8 __attribute__((ext_vector_type(8)));
typedef float f32x4 __attribute__((ext_vector_type(4)));

#define B_ROWS 8192

__device__ __forceinline__ float sigmoid_f(float x) {
    return 1.0f / (1.0f + __expf(-x));
}
__device__ __forceinline__ float tanh_f(float x) {
    return 1.0f - 2.0f / (__expf(2.0f * x) + 1.0f);
}

// ---------------------------------------------------------------------------
// Triple-buffered GEMM core: C[M,N] = A[M,K] @ W[N,K]^T + bias.
// Block tile BM x 128, BK=32, 4 waves; wave tile (BM/2) x 64 via
// mfma_f32_16x16x32_bf16. sA: 3 x BM x 32, sB: 3 x 128 x 32 (bf16).
// epi 0: out_bf = bf16(val)
// epi 1: out_bf = bf16(aux_f32 * sigmoid(val))        (forget gate)
// epi 2: out_f32 = float(aux_bf) * sigmoid(val)       (output gate)
// epi 3: out_bf[gcol*tld + grow] = bf16(val)          (transposed store)
// ---------------------------------------------------------------------------
template <int BM>
__device__ __forceinline__ void gemm_core_tb(
    bf16* sA, bf16* sB,
    const bf16* __restrict__ A, int lda,
    const bf16* __restrict__ W, int ldw,
    const float* __restrict__ bias,
    int N, int K, int brow, int bcol, int epi,
    bf16* __restrict__ out_bf, float* __restrict__ out_f32,
    const float* __restrict__ aux_f32, const bf16* __restrict__ aux_bf,
    int tld)
{
    constexpr int AI = BM / 32;
    const int tid  = threadIdx.x;
    const int lane = tid & 63;
    const int wave = tid >> 6;
    const int wr   = (wave & 1) * (BM / 2);
    const int wc   = (wave >> 1) * 64;
    const int lrow = lane & 15;
    const int lq   = lane >> 4;

    f32x4 acc[AI][4];
#pragma unroll
    for (int i = 0; i < AI; ++i)
#pragma unroll
        for (int j = 0; j < 4; ++j) {
            f32x4 z = {0.0f, 0.0f, 0.0f, 0.0f};
            acc[i][j] = z;
        }

    // stage tile (k0) into buffers dA/dB. LDS dest linear (rule #21); swizzle
    // applied by permuting the GLOBAL source column within each row-pair.
    auto stage = [&](bf16* dA, bf16* dB, int k0) {
#pragma unroll
        for (int i = 0; i < BM / 64; ++i) {
            const int s   = tid + i * 256;
            const int row = s >> 2;
            const int col = (((s & 3) ^ ((s >> 3) & 3)) << 3);
            const bf16* gp = A + (size_t)(brow + row) * lda + (k0 + col);
            __builtin_amdgcn_global_load_lds(
                (const __attribute__((address_space(1))) void*)gp,
                (__attribute__((address_space(3))) void*)(&dA[s * 8]),
                16, 0, 0);
        }
#pragma unroll
        for (int i = 0; i < 2; ++i) {
            const int s   = tid + i * 256;
            const int row = s >> 2;
            const int col = (((s & 3) ^ ((s >> 3) & 3)) << 3);
            const bf16* gp = W + (size_t)(bcol + row) * ldw + (k0 + col);
            __builtin_amdgcn_global_load_lds(
                (const __attribute__((address_space(1))) void*)gp,
                (__attribute__((address_space(3))) void*)(&dB[s * 8]),
                16, 0, 0);
        }
    };

    // counted wait: leave exactly one stage's loads (LPS) in flight
#define WAIT_LPS()                                                   \
    do {                                                             \
        if constexpr (BM == 128)                                     \
            asm volatile("s_waitcnt vmcnt(4)" ::: "memory");         \
        else                                                         \
            asm volatile("s_waitcnt vmcnt(3)" ::: "memory");         \
    } while (0)

    const int NT = K >> 5;

    bf16* a0 = sA;               bf16* b0 = sB;
    bf16* a1 = sA + BM * 32;     bf16* b1 = sB + 4096;
    bf16* a2 = sA + 2 * BM * 32; bf16* b2 = sB + 2 * 4096;

    // prologue: tiles 0 and 1 in flight; wait tile 0 only (vmcnt leaves
    // tile 1's LPS loads outstanding)
    stage(a0, b0, 0);
    stage(a1, b1, NT > 1 ? 32 : 0);
    WAIT_LPS();
    __builtin_amdgcn_s_barrier();
    __builtin_amdgcn_sched_barrier(0);

    for (int kt = 0; kt < NT; ++kt) {
        // fragment reads from buf0 (swizzled chunk: lq ^ ((r>>1)&3))
        bf16x8 av[AI], bv[4];
#pragma unroll
        for (int i = 0; i < AI; ++i) {
            const int r = wr + i * 16 + lrow;
            av[i] = *(const bf16x8*)&a0[r * 32 + ((lq ^ ((r >> 1) & 3)) << 3)];
        }
#pragma unroll
        for (int j = 0; j < 4; ++j) {
            const int r = wc + j * 16 + lrow;
            bv[j] = *(const bf16x8*)&b0[r * 32 + ((lq ^ ((r >> 1) & 3)) << 3)];
        }

        // issue tile kt+2 into the free buffer (tail: re-stage last tile to
        // keep the vmcnt FIFO accounting uniform; nobody reads it)
        const int kn = (kt + 2 < NT ? kt + 2 : NT - 1) << 5;
        stage(a2, b2, kn);

        // compiler inserts lgkm waits for av/bv before first use
#pragma unroll
        for (int i = 0; i < AI; ++i)
#pragma unroll
            for (int j = 0; j < 4; ++j)
                acc[i][j] = __builtin_amdgcn_mfma_f32_16x16x32_bf16(
                    av[i], bv[j], acc[i][j], 0, 0, 0);

        __builtin_amdgcn_sched_barrier(0);
        WAIT_LPS();                       // tile kt+1 landed; kt+2 in flight
        __builtin_amdgcn_s_barrier();
        __builtin_amdgcn_sched_barrier(0);

        // rotate buffers: (0,1,2) <- (1,2,0)
        bf16* ta = a0; a0 = a1; a1 = a2; a2 = ta;
        bf16* tb = b0; b0 = b1; b1 = b2; b2 = tb;
    }

    // drain redundant tail stages before epilogue / block exit
    asm volatile("s_waitcnt vmcnt(0)" ::: "memory");
#undef WAIT_LPS

    // epilogue: C/D layout col = lane&15, row = (lane>>4)*4 + reg
#pragma unroll
    for (int j = 0; j < 4; ++j) {
        const int gcol = bcol + wc + j * 16 + lrow;
        const float bj = bias ? bias[gcol] : 0.0f;
#pragma unroll
        for (int i = 0; i < AI; ++i) {
            const int growb = brow + wr + i * 16 + lq * 4;
#pragma unroll
            for (int r = 0; r < 4; ++r) {
                const int grow = growb + r;
                const float val = acc[i][j][r] + bj;
                if (epi == 0) {
                    out_bf[(size_t)grow * N + gcol] = (bf16)val;
                } else if (epi == 1) {
                    const size_t idx = (size_t)grow * N + gcol;
                    out_bf[idx] = (bf16)(aux_f32[idx] * sigmoid_f(val));
                } else if (epi == 2) {
                    const size_t idx = (size_t)grow * N + gcol;
                    out_f32[idx] = (float)aux_bf[idx] * sigmoid_f(val);
                } else {
                    out_bf[(size_t)gcol * tld + grow] = (bf16)val;
                }
            }
        }
    }
}

// 1-D grid, y-fastest decode: by = id % nby, bx = id / nby. Co-resident
// blocks then share A row-tiles (same bx phase) -> L3 absorbs the re-reads.
__global__ __launch_bounds__(256, 2) void gemm128_k(
    const bf16* __restrict__ A, int lda, const bf16* __restrict__ W, int ldw,
    const float* __restrict__ bias, int N, int K, int epi,
    bf16* __restrict__ out_bf, float* __restrict__ out_f32,
    const float* __restrict__ aux_f32, const bf16* __restrict__ aux_bf,
    int tld, int nby)
{
    __shared__ bf16 sA[3 * 128 * 32];
    __shared__ bf16 sB[3 * 128 * 32];
    const int by = blockIdx.x % nby;
    const int bx = blockIdx.x / nby;
    gemm_core_tb<128>(sA, sB, A, lda, W, ldw, bias, N, K,
                      by * 128, bx * 128, epi,
                      out_bf, out_f32, aux_f32, aux_bf, tld);
}

__global__ __launch_bounds__(256, 2) void gemm64_k(
    const bf16* __restrict__ A, int lda, const bf16* __restrict__ W, int ldw,
    const float* __restrict__ bias, int N, int K, int epi,
    bf16* __restrict__ out_bf, float* __restrict__ out_f32,
    const float* __restrict__ aux_f32, const bf16* __restrict__ aux_bf,
    int tld, int nby)
{
    __shared__ bf16 sA[3 * 64 * 32];
    __shared__ bf16 sB[3 * 128 * 32];
    const int by = blockIdx.x % nby;
    const int bx = blockIdx.x / nby;
    gemm_core_tb<64>(sA, sB, A, lda, W, ldw, bias, N, K,
                     by * 64, bx * 128, epi,
                     out_bf, out_f32, aux_f32, aux_bf, tld);
}

// ---------------------------------------------------------------------------
// Elementwise / small helpers
// ---------------------------------------------------------------------------

// One launch casting all 5 front weights. Chunk = 4 floats. Segment table
// hardcoded for this problem's sizes.
__global__ void cast_weights_k(
    const float* __restrict__ wv, const float* __restrict__ wop,
    const float* __restrict__ wih, const float* __restrict__ wfg,
    const float* __restrict__ wog,
    bf16* __restrict__ dv, bf16* __restrict__ dop, bf16* __restrict__ dih,
    bf16* __restrict__ dfg, bf16* __restrict__ dog)
{
    int c = blockIdx.x * 256 + threadIdx.x;  // [0, 2097152)
    const float* s;
    bf16* d;
    int o;
    if (c < 262144)        { s = wv;  d = dv;  o = c; }
    else if (c < 524288)   { s = wop; d = dop; o = c - 262144; }
    else if (c < 1310720)  { s = wih; d = dih; o = c - 524288; }
    else if (c < 1835008)  { s = wfg; d = dfg; o = c - 1310720; }
    else                   { s = wog; d = dog; o = c - 1835008; }
    f32x4 v = ((const f32x4*)s)[o];
    bf16x4 t = {(bf16)v[0], (bf16)v[1], (bf16)v[2], (bf16)v[3]};
    ((bf16x4*)d)[o] = t;
}

__global__ void cast_f32_bf16_k(const float* __restrict__ src,
                                bf16* __restrict__ dst, int n4) {
    int i = blockIdx.x * 256 + threadIdx.x;
    if (i >= n4) return;
    f32x4 v = ((const f32x4*)src)[i];
    bf16x4 o = {(bf16)v[0], (bf16)v[1], (bf16)v[2], (bf16)v[3]};
    ((bf16x4*)dst)[i] = o;
}

__global__ void build_cat_k(const float* __restrict__ mem,
                            const float* __restrict__ inp,
                            bf16* __restrict__ cat) {
    int i = blockIdx.x * 256 + threadIdx.x;
    int row = i >> 9;
    int c4  = i & 511;
    f32x4 v;
    if (c4 < 256)
        v = ((const f32x4*)mem)[(size_t)row * 256 + c4];
    else
        v = ((const f32x4*)inp)[(size_t)row * 256 + (c4 - 256)];
    bf16x4 o = {(bf16)v[0], (bf16)v[1], (bf16)v[2], (bf16)v[3]};
    ((bf16x4*)cat)[i] = o;
}

// src [R,C] f32  ->  dst [C,R] bf16
__global__ void transpose_cast_k(const float* __restrict__ src,
                                 bf16* __restrict__ dst, int R, int C) {
    __shared__ float t[32][33];
    int bx = blockIdx.x * 32;
    int by = blockIdx.y * 32;
    int tx = threadIdx.x & 31, ty = threadIdx.x >> 5;
#pragma unroll
    for (int i = 0; i < 32; i += 8)
        t[ty + i][tx] = src[(size_t)(by + ty + i) * C + bx + tx];
    __syncthreads();
#pragma unroll
    for (int i = 0; i < 32; i += 8)
        dst[(size_t)(bx + ty + i) * R + by + tx] = (bf16)t[tx][ty + i];
}

// y[n] = b[n] + sum_k W[n,k] * x[k]   (fp32; one wave per output row)
__global__ void gemv_k(const float* __restrict__ W, const float* __restrict__ x,
                       const float* __restrict__ b, float* __restrict__ y,
                       int K) {
    int n    = blockIdx.x * 4 + (threadIdx.x >> 6);
    int lane = threadIdx.x & 63;
    const float* row = W + (size_t)n * K;
    float s = 0.0f;
    for (int k = lane * 4; k < K; k += 256) {
        f32x4 w = *(const f32x4*)(row + k);
        f32x4 xv = *(const f32x4*)(x + k);
        s += w[0] * xv[0] + w[1] * xv[1] + w[2] * xv[2] + w[3] * xv[3];
    }
#pragma unroll
    for (int off = 32; off; off >>= 1) s += __shfl_down(s, off);
    if (lane == 0) y[n] = s + b[n];
}

// GRU combine, in place: upd (=gated buffer) = (1-z)*n + z*gated
__global__ void gru_combine_k(const bf16* __restrict__ gi,
                              const bf16* __restrict__ gh,
                              bf16* __restrict__ gated) {
    int i   = blockIdx.x * 256 + threadIdx.x;
    int row = i >> 7;
    int c   = (i & 127) << 3;
    size_t b3 = (size_t)row * 3072 + c;
    size_t b1 = (size_t)row * 1024 + c;
    bf16x8 gir = *(const bf16x8*)(gi + b3);
    bf16x8 giz = *(const bf16x8*)(gi + b3 + 1024);
    bf16x8 gin = *(const bf16x8*)(gi + b3 + 2048);
    bf16x8 ghr = *(const bf16x8*)(gh + b3);
    bf16x8 ghz = *(const bf16x8*)(gh + b3 + 1024);
    bf16x8 ghn = *(const bf16x8*)(gh + b3 + 2048);
    bf16x8 g   = *(const bf16x8*)(gated + b1);
    bf16x8 o;
#pragma unroll
    for (int e = 0; e < 8; ++e) {
        float r = sigmoid_f((float)gir[e] + (float)ghr[e]);
        float z = sigmoid_f((float)giz[e] + (float)ghz[e]);
        float n = tanh_f((float)gin[e] + r * (float)ghn[e]);
        o[e] = (bf16)((1.0f - z) * n + z * (float)g[e]);
    }
    *(bf16x8*)(gated + b1) = o;
}

__global__ void fill_ones_k(float* __restrict__ p, int n) {
    int i = blockIdx.x * 256 + threadIdx.x;
    if (i < n) p[i] = 1.0f;
}

// ---------------------------------------------------------------------------
// Launch
// ---------------------------------------------------------------------------
extern "C" void kernel_launch(void* const* d_in, const int* in_sizes, int n_in,
                              void* d_out, int out_size, void* d_ws,
                              size_t ws_size, hipStream_t stream) {
    const float* input      = (const float*)d_in[0];
    const float* prev       = (const float*)d_in[1];
    const float* in_proj_w  = (const float*)d_in[2];
    const float* in_proj_b  = (const float*)d_in[3];
    const float* out_proj_w = (const float*)d_in[4];
    const float* out_proj_b = (const float*)d_in[5];
    const float* ip_w       = (const float*)d_in[6];
    const float* ip_b       = (const float*)d_in[7];
    // d_in[8]/d_in[9] (mp_w/mp_b) dead: softmax over one key == 1
    const float* fg_w  = (const float*)d_in[10];
    const float* fg_b  = (const float*)d_in[11];
    const float* og_w  = (const float*)d_in[12];
    const float* og_b  = (const float*)d_in[13];
    const float* gih_w = (const float*)d_in[14];
    const float* gih_b = (const float*)d_in[15];
    const float* ghh_w = (const float*)d_in[16];
    const float* ghh_b = (const float*)d_in[17];
    float* out = (float*)d_out;

    // ---- workspace layout (152 MiB, overlaps respect dependency order)
    char* ws = (char*)d_ws;
    const size_t MB = 1024 * 1024;
    bf16* CAT   = (bf16*)(ws);             // [0,32M)  live until gi done
    bf16* WHHB  = (bf16*)(ws);             // 6M, cast AFTER gi (overlaps CAT)
    bf16* GI    = (bf16*)(ws + 32 * MB);   // [32,80M)
    bf16* GH    = (bf16*)(ws + 80 * MB);   // [80,128M) written late
    // temporaries inside the GH region (dead before GH is written):
    bf16* WVB   = (bf16*)(ws + 80 * MB);   // 2M
    bf16* WOPB  = (bf16*)(ws + 82 * MB);   // 2M
    bf16* WIHB  = (bf16*)(ws + 84 * MB);   // 6M
    bf16* WIPT  = (bf16*)(ws + 90 * MB);   // 2M
    bf16* T1T   = (bf16*)(ws + 92 * MB);   // 2M
    bf16* T2T   = (bf16*)(ws + 94 * MB);   // 2M
    bf16* WFGB  = (bf16*)(ws + 96 * MB);   // 4M
    float* T1B  = (float*)(ws + 100 * MB);
    float* T2B  = (float*)(ws + 100 * MB + 8192);
    float* T3B  = (float*)(ws + 100 * MB + 16384);
    bf16* GATED = (bf16*)(ws + 128 * MB);  // [128,144M); becomes UPD in place
    bf16* WCOMB = (bf16*)(ws + 144 * MB);  // [144,150M)
    bf16* WOGB  = (bf16*)(ws + 150 * MB);  // [150,152M)

    const int M = B_ROWS;
    dim3 blk(256);

    // 1. activations -> bf16 concat
    build_cat_k<<<dim3((M * 2048 / 4) / 256), blk, 0, stream>>>(prev, input, CAT);
    // 2. all front weight casts in one launch
    cast_weights_k<<<dim3(8192), blk, 0, stream>>>(
        in_proj_w + 2048 * 1024, out_proj_w, gih_w, fg_w, og_w,
        WVB, WOPB, WIHB, WFGB, WOGB);
    // 3. Wip^T (bf16)
    transpose_cast_k<<<dim3(32, 32), blk, 0, stream>>>(ip_w, WIPT, 1024, 1024);
    // 4. bias chain (fp32, exact)
    gemv_k<<<dim3(256), blk, 0, stream>>>(in_proj_w + 2048 * 1024, ip_b, in_proj_b + 2048, T1B, 1024);
    gemv_k<<<dim3(256), blk, 0, stream>>>(out_proj_w, T1B, out_proj_b, T2B, 1024);
    gemv_k<<<dim3(768), blk, 0, stream>>>(gih_w, T2B, gih_b, T3B, 1024);
    // 5-7. weight composition: Wcomb = Wih @ Wop @ Wv @ Wip
    gemm64_k<<<dim3(128), blk, 0, stream>>>(WVB, 1024, WIPT, 1024, nullptr,
        1024, 1024, 3, T1T, nullptr, nullptr, nullptr, 1024, 16);  // (Wv@Wip)^T
    gemm64_k<<<dim3(128), blk, 0, stream>>>(WOPB, 1024, T1T, 1024, nullptr,
        1024, 1024, 3, T2T, nullptr, nullptr, nullptr, 1024, 16);  // (Wop@..)^T
    gemm64_k<<<dim3(384), blk, 0, stream>>>(WIHB, 1024, T2T, 1024, nullptr,
        1024, 1024, 0, WCOMB, nullptr, nullptr, nullptr, 0, 48);   // Wcomb
    // 8. gated = prev * sigmoid(cat @ Wfg^T + bfg)
    gemm128_k<<<dim3(512), blk, 0, stream>>>(CAT, 2048, WFGB, 2048,
        fg_b, 1024, 2048, 1, GATED, nullptr, prev, nullptr, 0, 64);
    // 9. gi = x @ Wcomb^T + bcomb
    gemm128_k<<<dim3(1536), blk, 0, stream>>>(CAT + 1024, 2048, WCOMB,
        1024, T3B, 3072, 1024, 0, GI, nullptr, nullptr, nullptr, 0, 64);
    // 10. Whh cast (CAT now dead)
    cast_f32_bf16_k<<<dim3(3072), blk, 0, stream>>>(ghh_w, WHHB, 3072 * 1024 / 4);
    // 11. gh = gated @ Whh^T + bhh
    gemm128_k<<<dim3(1536), blk, 0, stream>>>(GATED, 1024, WHHB, 1024,
        ghh_b, 3072, 1024, 0, GH, nullptr, nullptr, nullptr, 0, 64);
    // 12. GRU combine (in place: GATED becomes UPD)
    gru_combine_k<<<dim3(M * 1024 / 8 / 256), blk, 0, stream>>>(GI, GH, GATED);
    // 13. out = upd * sigmoid(upd @ Wog^T + bog)
    gemm128_k<<<dim3(512), blk, 0, stream>>>(GATED, 1024, WOGB, 1024,
        og_b, 1024, 1024, 2, nullptr, out, nullptr, GATED, 0, 64);
    // 14. attention weights == 1.0
    fill_ones_k<<<dim3(32), blk, 0, stream>>>(out + (size_t)M * 1024, M);
}

// Round 5
// 491.143 us; speedup vs baseline: 1.0827x; 1.0827x over previous
//
#include <hip/hip_runtime.h>
#include <cstdint>
#include <cstddef>

// ---------------------------------------------------------------------------
// DynamicMemoryCell on MI355X (gfx950) — round 9
//
// Math: softmax over 1 key == 1 -> attn == v; q/k/pm dead.
// Linear chain pi->v->ctx->gi collapsed: Wcomb = Wih@Wop@Wv@Wip (per call).
//
// Round-9 vs round-8: round-8 showed counted-vmcnt depth works (105->90us)
// but MfmaUtil caps ~24% because the 128^2 tile's per-K-step resource mix is
// LDS/barrier-dominated (32KB ds_read + 16KB lds-write vs 78cyc MFMA), and
// the scattered 2B epilogue writes amplify 48MB -> 104MB (WRITE_SIZE).
//   * NEW gemm256x128_k for gi/gh: 256x128 block tile, 4 waves, wave tile
//     128x64 (acc[8][4]) -> 1.33x better LDS-bytes/FLOP, 2x epilogue
//     amortization. Triple-buffered BK=32 (72 KiB, 2 blocks/CU), counted
//     s_waitcnt vmcnt(6). Grid 768 blocks.
//   * LDS-staged coalesced epilogue (epi0 path): stage bf16(acc+bias) to
//     LDS (stride 136 = 2-way-max conflicts), flush as b128 stores in 256B
//     row segments -> WRITE_SIZE ~= output size.
//   * fg/og (N=1024) stay on the round-8 triple-buffered 128^2 kernel
//     (256-tile grids would under-fill: round-2 lesson).
// ---------------------------------------------------------------------------

typedef __bf16 bf16;
typedef bf16 bf16x4 __attribute__((ext_vector_type(4)));
typedef bf16 bf16x8 __attribute__((ext_vector_type(8)));
typedef float f32x4 __attribute__((ext_vector_type(4)));

#define B_ROWS 8192

__device__ __forceinline__ float sigmoid_f(float x) {
    return 1.0f / (1.0f + __expf(-x));
}
__device__ __forceinline__ float tanh_f(float x) {
    return 1.0f - 2.0f / (__expf(2.0f * x) + 1.0f);
}

// ---------------------------------------------------------------------------
// 256x128 triple-buffered GEMM (gi/gh): C[M,N] = A[M,K] @ W[N,K]^T + bias,
// C in bf16. 4 waves (2M x 2N), wave tile 128x64, acc[8][4] f32x4.
// LDS: sA 3x256x32 + sB 3x128x32 bf16 = 72 KiB; reused as C-stage (256x136
// bf16 = 68 KiB) in the epilogue.
// Counted vmcnt: 6 loads/stage; steady state 12 outstanding, wait vmcnt(6).
// ---------------------------------------------------------------------------
__global__ __launch_bounds__(256, 2) void gemm256x128_k(
    const bf16* __restrict__ A, int lda,
    const bf16* __restrict__ W, int ldw,
    const float* __restrict__ bias, int N, int K,
    bf16* __restrict__ out_bf, int nby)
{
    __shared__ bf16 lds[36864];          // 72 KiB
    bf16* sA = lds;                       // 3 x 256 x 32
    bf16* sB = lds + 3 * 256 * 32;        // 3 x 128 x 32

    const int tid  = threadIdx.x;
    const int lane = tid & 63;
    const int wave = tid >> 6;
    const int wm   = wave >> 1;          // 0..1 (M half: 128 rows)
    const int wn   = wave & 1;           // 0..1 (N half: 64 cols)
    const int lrow = lane & 15;
    const int lq   = lane >> 4;

    const int by   = blockIdx.x % nby;   // y-fastest: co-residents share W
    const int bx   = blockIdx.x / nby;
    const int brow = by * 256;
    const int bcol = bx * 128;

    f32x4 acc[8][4];
#pragma unroll
    for (int i = 0; i < 8; ++i)
#pragma unroll
        for (int j = 0; j < 4; ++j) {
            f32x4 z = {0.0f, 0.0f, 0.0f, 0.0f};
            acc[i][j] = z;
        }

    // stage one BK=32 tile: A 4 insts (256 rows), B 2 insts (128 rows).
    // LDS dest linear (rule #21); swizzle via permuted GLOBAL source col.
    auto stage = [&](bf16* dA, bf16* dB, int k0) {
#pragma unroll
        for (int i = 0; i < 4; ++i) {
            const int s   = tid + i * 256;
            const int row = s >> 2;
            const int col = (((s & 3) ^ ((s >> 3) & 3)) << 3);
            const bf16* gp = A + (size_t)(brow + row) * lda + (k0 + col);
            __builtin_amdgcn_global_load_lds(
                (const __attribute__((address_space(1))) void*)gp,
                (__attribute__((address_space(3))) void*)(&dA[s * 8]),
                16, 0, 0);
        }
#pragma unroll
        for (int i = 0; i < 2; ++i) {
            const int s   = tid + i * 256;
            const int row = s >> 2;
            const int col = (((s & 3) ^ ((s >> 3) & 3)) << 3);
            const bf16* gp = W + (size_t)(bcol + row) * ldw + (k0 + col);
            __builtin_amdgcn_global_load_lds(
                (const __attribute__((address_space(1))) void*)gp,
                (__attribute__((address_space(3))) void*)(&dB[s * 8]),
                16, 0, 0);
        }
    };

    const int NT = K >> 5;

    bf16* a0 = sA;                bf16* b0 = sB;
    bf16* a1 = sA + 256 * 32;     bf16* b1 = sB + 128 * 32;
    bf16* a2 = sA + 2 * 256 * 32; bf16* b2 = sB + 2 * 128 * 32;

    stage(a0, b0, 0);
    stage(a1, b1, 32);
    asm volatile("s_waitcnt vmcnt(6)" ::: "memory");  // tile 0 landed
    __builtin_amdgcn_s_barrier();
    __builtin_amdgcn_sched_barrier(0);

    for (int kt = 0; kt < NT; ++kt) {
        bf16x8 av[8], bv[4];
#pragma unroll
        for (int i = 0; i < 8; ++i) {
            const int r = wm * 128 + i * 16 + lrow;
            av[i] = *(const bf16x8*)&a0[r * 32 + ((lq ^ ((r >> 1) & 3)) << 3)];
        }
#pragma unroll
        for (int j = 0; j < 4; ++j) {
            const int r = wn * 64 + j * 16 + lrow;
            bv[j] = *(const bf16x8*)&b0[r * 32 + ((lq ^ ((r >> 1) & 3)) << 3)];
        }

        // tile kt+2 into the free buffer (tail re-stages: uniform FIFO)
        const int kn = (kt + 2 < NT ? kt + 2 : NT - 1) << 5;
        stage(a2, b2, kn);

#pragma unroll
        for (int i = 0; i < 8; ++i)
#pragma unroll
            for (int j = 0; j < 4; ++j)
                acc[i][j] = __builtin_amdgcn_mfma_f32_16x16x32_bf16(
                    av[i], bv[j], acc[i][j], 0, 0, 0);

        __builtin_amdgcn_sched_barrier(0);
        asm volatile("s_waitcnt vmcnt(6)" ::: "memory"); // kt+1 landed
        __builtin_amdgcn_s_barrier();
        __builtin_amdgcn_sched_barrier(0);

        bf16* ta = a0; a0 = a1; a1 = a2; a2 = ta;
        bf16* tb = b0; b0 = b1; b1 = b2; b2 = tb;
    }

    // drain redundant tail stages, then LDS is free for the C-stage
    asm volatile("s_waitcnt vmcnt(0)" ::: "memory");

    // ---- epilogue: stage bf16(acc+bias) to LDS, flush coalesced -----------
    // cb stride 136 elems (272B): write groups (rows +4 apart) land on
    // disjoint/2-way bank sets; 16B reads stay aligned (136 % 8 == 0).
    bf16* cb = lds;
#pragma unroll
    for (int j = 0; j < 4; ++j) {
        const int col = wn * 64 + j * 16 + lrow;
        const float bj = bias[bcol + col];
#pragma unroll
        for (int i = 0; i < 8; ++i) {
            const int rowb = wm * 128 + i * 16 + lq * 4;
#pragma unroll
            for (int r = 0; r < 4; ++r)
                cb[(rowb + r) * 136 + col] = (bf16)(acc[i][j][r] + bj);
        }
    }
    __syncthreads();
#pragma unroll
    for (int p = 0; p < 16; ++p) {
        const int row = p * 16 + (tid >> 4);
        const int col = (tid & 15) * 8;
        bf16x8 v = *(const bf16x8*)&cb[row * 136 + col];
        *(bf16x8*)&out_bf[(size_t)(brow + row) * N + bcol + col] = v;
    }
}

// ---------------------------------------------------------------------------
// Triple-buffered GEMM core (fg/og + small GEMMs): C = A @ W^T + bias.
// Block tile BM x 128, BK=32, 4 waves; wave tile (BM/2) x 64.
// epi 0: out_bf = bf16(val)
// epi 1: out_bf = bf16(aux_f32 * sigmoid(val))        (forget gate)
// epi 2: out_f32 = float(aux_bf) * sigmoid(val)       (output gate)
// epi 3: out_bf[gcol*tld + grow] = bf16(val)          (transposed store)
// ---------------------------------------------------------------------------
template <int BM>
__device__ __forceinline__ void gemm_core_tb(
    bf16* sA, bf16* sB,
    const bf16* __restrict__ A, int lda,
    const bf16* __restrict__ W, int ldw,
    const float* __restrict__ bias,
    int N, int K, int brow, int bcol, int epi,
    bf16* __restrict__ out_bf, float* __restrict__ out_f32,
    const float* __restrict__ aux_f32, const bf16* __restrict__ aux_bf,
    int tld)
{
    constexpr int AI = BM / 32;
    const int tid  = threadIdx.x;
    const int lane = tid & 63;
    const int wave = tid >> 6;
    const int wr   = (wave & 1) * (BM / 2);
    const int wc   = (wave >> 1) * 64;
    const int lrow = lane & 15;
    const int lq   = lane >> 4;

    f32x4 acc[AI][4];
#pragma unroll
    for (int i = 0; i < AI; ++i)
#pragma unroll
        for (int j = 0; j < 4; ++j) {
            f32x4 z = {0.0f, 0.0f, 0.0f, 0.0f};
            acc[i][j] = z;
        }

    auto stage = [&](bf16* dA, bf16* dB, int k0) {
#pragma unroll
        for (int i = 0; i < BM / 64; ++i) {
            const int s   = tid + i * 256;
            const int row = s >> 2;
            const int col = (((s & 3) ^ ((s >> 3) & 3)) << 3);
            const bf16* gp = A + (size_t)(brow + row) * lda + (k0 + col);
            __builtin_amdgcn_global_load_lds(
                (const __attribute__((address_space(1))) void*)gp,
                (__attribute__((address_space(3))) void*)(&dA[s * 8]),
                16, 0, 0);
        }
#pragma unroll
        for (int i = 0; i < 2; ++i) {
            const int s   = tid + i * 256;
            const int row = s >> 2;
            const int col = (((s & 3) ^ ((s >> 3) & 3)) << 3);
            const bf16* gp = W + (size_t)(bcol + row) * ldw + (k0 + col);
            __builtin_amdgcn_global_load_lds(
                (const __attribute__((address_space(1))) void*)gp,
                (__attribute__((address_space(3))) void*)(&dB[s * 8]),
                16, 0, 0);
        }
    };

#define WAIT_LPS()                                                   \
    do {                                                             \
        if constexpr (BM == 128)                                     \
            asm volatile("s_waitcnt vmcnt(4)" ::: "memory");         \
        else                                                         \
            asm volatile("s_waitcnt vmcnt(3)" ::: "memory");         \
    } while (0)

    const int NT = K >> 5;

    bf16* a0 = sA;               bf16* b0 = sB;
    bf16* a1 = sA + BM * 32;     bf16* b1 = sB + 4096;
    bf16* a2 = sA + 2 * BM * 32; bf16* b2 = sB + 2 * 4096;

    stage(a0, b0, 0);
    stage(a1, b1, NT > 1 ? 32 : 0);
    WAIT_LPS();
    __builtin_amdgcn_s_barrier();
    __builtin_amdgcn_sched_barrier(0);

    for (int kt = 0; kt < NT; ++kt) {
        bf16x8 av[AI], bv[4];
#pragma unroll
        for (int i = 0; i < AI; ++i) {
            const int r = wr + i * 16 + lrow;
            av[i] = *(const bf16x8*)&a0[r * 32 + ((lq ^ ((r >> 1) & 3)) << 3)];
        }
#pragma unroll
        for (int j = 0; j < 4; ++j) {
            const int r = wc + j * 16 + lrow;
            bv[j] = *(const bf16x8*)&b0[r * 32 + ((lq ^ ((r >> 1) & 3)) << 3)];
        }

        const int kn = (kt + 2 < NT ? kt + 2 : NT - 1) << 5;
        stage(a2, b2, kn);

#pragma unroll
        for (int i = 0; i < AI; ++i)
#pragma unroll
            for (int j = 0; j < 4; ++j)
                acc[i][j] = __builtin_amdgcn_mfma_f32_16x16x32_bf16(
                    av[i], bv[j], acc[i][j], 0, 0, 0);

        __builtin_amdgcn_sched_barrier(0);
        WAIT_LPS();
        __builtin_amdgcn_s_barrier();
        __builtin_amdgcn_sched_barrier(0);

        bf16* ta = a0; a0 = a1; a1 = a2; a2 = ta;
        bf16* tb = b0; b0 = b1; b1 = b2; b2 = tb;
    }

    asm volatile("s_waitcnt vmcnt(0)" ::: "memory");
#undef WAIT_LPS

    // epilogue: C/D layout col = lane&15, row = (lane>>4)*4 + reg
#pragma unroll
    for (int j = 0; j < 4; ++j) {
        const int gcol = bcol + wc + j * 16 + lrow;
        const float bj = bias ? bias[gcol] : 0.0f;
#pragma unroll
        for (int i = 0; i < AI; ++i) {
            const int growb = brow + wr + i * 16 + lq * 4;
#pragma unroll
            for (int r = 0; r < 4; ++r) {
                const int grow = growb + r;
                const float val = acc[i][j][r] + bj;
                if (epi == 0) {
                    out_bf[(size_t)grow * N + gcol] = (bf16)val;
                } else if (epi == 1) {
                    const size_t idx = (size_t)grow * N + gcol;
                    out_bf[idx] = (bf16)(aux_f32[idx] * sigmoid_f(val));
                } else if (epi == 2) {
                    const size_t idx = (size_t)grow * N + gcol;
                    out_f32[idx] = (float)aux_bf[idx] * sigmoid_f(val);
                } else {
                    out_bf[(size_t)gcol * tld + grow] = (bf16)val;
                }
            }
        }
    }
}

__global__ __launch_bounds__(256, 2) void gemm128_k(
    const bf16* __restrict__ A, int lda, const bf16* __restrict__ W, int ldw,
    const float* __restrict__ bias, int N, int K, int epi,
    bf16* __restrict__ out_bf, float* __restrict__ out_f32,
    const float* __restrict__ aux_f32, const bf16* __restrict__ aux_bf,
    int tld, int nby)
{
    __shared__ bf16 sA[3 * 128 * 32];
    __shared__ bf16 sB[3 * 128 * 32];
    const int by = blockIdx.x % nby;
    const int bx = blockIdx.x / nby;
    gemm_core_tb<128>(sA, sB, A, lda, W, ldw, bias, N, K,
                      by * 128, bx * 128, epi,
                      out_bf, out_f32, aux_f32, aux_bf, tld);
}

__global__ __launch_bounds__(256, 2) void gemm64_k(
    const bf16* __restrict__ A, int lda, const bf16* __restrict__ W, int ldw,
    const float* __restrict__ bias, int N, int K, int epi,
    bf16* __restrict__ out_bf, float* __restrict__ out_f32,
    const float* __restrict__ aux_f32, const bf16* __restrict__ aux_bf,
    int tld, int nby)
{
    __shared__ bf16 sA[3 * 64 * 32];
    __shared__ bf16 sB[3 * 128 * 32];
    const int by = blockIdx.x % nby;
    const int bx = blockIdx.x / nby;
    gemm_core_tb<64>(sA, sB, A, lda, W, ldw, bias, N, K,
                     by * 64, bx * 128, epi,
                     out_bf, out_f32, aux_f32, aux_bf, tld);
}

// ---------------------------------------------------------------------------
// Elementwise / small helpers
// ---------------------------------------------------------------------------

__global__ void cast_weights_k(
    const float* __restrict__ wv, const float* __restrict__ wop,
    const float* __restrict__ wih, const float* __restrict__ wfg,
    const float* __restrict__ wog,
    bf16* __restrict__ dv, bf16* __restrict__ dop, bf16* __restrict__ dih,
    bf16* __restrict__ dfg, bf16* __restrict__ dog)
{
    int c = blockIdx.x * 256 + threadIdx.x;  // [0, 2097152)
    const float* s;
    bf16* d;
    int o;
    if (c < 262144)        { s = wv;  d = dv;  o = c; }
    else if (c < 524288)   { s = wop; d = dop; o = c - 262144; }
    else if (c < 1310720)  { s = wih; d = dih; o = c - 524288; }
    else if (c < 1835008)  { s = wfg; d = dfg; o = c - 1310720; }
    else                   { s = wog; d = dog; o = c - 1835008; }
    f32x4 v = ((const f32x4*)s)[o];
    bf16x4 t = {(bf16)v[0], (bf16)v[1], (bf16)v[2], (bf16)v[3]};
    ((bf16x4*)d)[o] = t;
}

__global__ void cast_f32_bf16_k(const float* __restrict__ src,
                                bf16* __restrict__ dst, int n4) {
    int i = blockIdx.x * 256 + threadIdx.x;
    if (i >= n4) return;
    f32x4 v = ((const f32x4*)src)[i];
    bf16x4 o = {(bf16)v[0], (bf16)v[1], (bf16)v[2], (bf16)v[3]};
    ((bf16x4*)dst)[i] = o;
}

__global__ void build_cat_k(const float* __restrict__ mem,
                            const float* __restrict__ inp,
                            bf16* __restrict__ cat) {
    int i = blockIdx.x * 256 + threadIdx.x;
    int row = i >> 9;
    int c4  = i & 511;
    f32x4 v;
    if (c4 < 256)
        v = ((const f32x4*)mem)[(size_t)row * 256 + c4];
    else
        v = ((const f32x4*)inp)[(size_t)row * 256 + (c4 - 256)];
    bf16x4 o = {(bf16)v[0], (bf16)v[1], (bf16)v[2], (bf16)v[3]};
    ((bf16x4*)cat)[i] = o;
}

// src [R,C] f32  ->  dst [C,R] bf16
__global__ void transpose_cast_k(const float* __restrict__ src,
                                 bf16* __restrict__ dst, int R, int C) {
    __shared__ float t[32][33];
    int bx = blockIdx.x * 32;
    int by = blockIdx.y * 32;
    int tx = threadIdx.x & 31, ty = threadIdx.x >> 5;
#pragma unroll
    for (int i = 0; i < 32; i += 8)
        t[ty + i][tx] = src[(size_t)(by + ty + i) * C + bx + tx];
    __syncthreads();
#pragma unroll
    for (int i = 0; i < 32; i += 8)
        dst[(size_t)(bx + ty + i) * R + by + tx] = (bf16)t[tx][ty + i];
}

// y[n] = b[n] + sum_k W[n,k] * x[k]   (fp32; one wave per output row)
__global__ void gemv_k(const float* __restrict__ W, const float* __restrict__ x,
                       const float* __restrict__ b, float* __restrict__ y,
                       int K) {
    int n    = blockIdx.x * 4 + (threadIdx.x >> 6);
    int lane = threadIdx.x & 63;
    const float* row = W + (size_t)n * K;
    float s = 0.0f;
    for (int k = lane * 4; k < K; k += 256) {
        f32x4 w = *(const f32x4*)(row + k);
        f32x4 xv = *(const f32x4*)(x + k);
        s += w[0] * xv[0] + w[1] * xv[1] + w[2] * xv[2] + w[3] * xv[3];
    }
#pragma unroll
    for (int off = 32; off; off >>= 1) s += __shfl_down(s, off);
    if (lane == 0) y[n] = s + b[n];
}

// GRU combine, in place: upd (=gated buffer) = (1-z)*n + z*gated
__global__ void gru_combine_k(const bf16* __restrict__ gi,
                              const bf16* __restrict__ gh,
                              bf16* __restrict__ gated) {
    int i   = blockIdx.x * 256 + threadIdx.x;
    int row = i >> 7;
    int c   = (i & 127) << 3;
    size_t b3 = (size_t)row * 3072 + c;
    size_t b1 = (size_t)row * 1024 + c;
    bf16x8 gir = *(const bf16x8*)(gi + b3);
    bf16x8 giz = *(const bf16x8*)(gi + b3 + 1024);
    bf16x8 gin = *(const bf16x8*)(gi + b3 + 2048);
    bf16x8 ghr = *(const bf16x8*)(gh + b3);
    bf16x8 ghz = *(const bf16x8*)(gh + b3 + 1024);
    bf16x8 ghn = *(const bf16x8*)(gh + b3 + 2048);
    bf16x8 g   = *(const bf16x8*)(gated + b1);
    bf16x8 o;
#pragma unroll
    for (int e = 0; e < 8; ++e) {
        float r = sigmoid_f((float)gir[e] + (float)ghr[e]);
        float z = sigmoid_f((float)giz[e] + (float)ghz[e]);
        float n = tanh_f((float)gin[e] + r * (float)ghn[e]);
        o[e] = (bf16)((1.0f - z) * n + z * (float)g[e]);
    }
    *(bf16x8*)(gated + b1) = o;
}

__global__ void fill_ones_k(float* __restrict__ p, int n) {
    int i = blockIdx.x * 256 + threadIdx.x;
    if (i < n) p[i] = 1.0f;
}

// ---------------------------------------------------------------------------
// Launch
// ---------------------------------------------------------------------------
extern "C" void kernel_launch(void* const* d_in, const int* in_sizes, int n_in,
                              void* d_out, int out_size, void* d_ws,
                              size_t ws_size, hipStream_t stream) {
    const float* input      = (const float*)d_in[0];
    const float* prev       = (const float*)d_in[1];
    const float* in_proj_w  = (const float*)d_in[2];
    const float* in_proj_b  = (const float*)d_in[3];
    const float* out_proj_w = (const float*)d_in[4];
    const float* out_proj_b = (const float*)d_in[5];
    const float* ip_w       = (const float*)d_in[6];
    const float* ip_b       = (const float*)d_in[7];
    // d_in[8]/d_in[9] (mp_w/mp_b) dead: softmax over one key == 1
    const float* fg_w  = (const float*)d_in[10];
    const float* fg_b  = (const float*)d_in[11];
    const float* og_w  = (const float*)d_in[12];
    const float* og_b  = (const float*)d_in[13];
    const float* gih_w = (const float*)d_in[14];
    const float* gih_b = (const float*)d_in[15];
    const float* ghh_w = (const float*)d_in[16];
    const float* ghh_b = (const float*)d_in[17];
    float* out = (float*)d_out;

    // ---- workspace layout (152 MiB, overlaps respect dependency order)
    char* ws = (char*)d_ws;
    const size_t MB = 1024 * 1024;
    bf16* CAT   = (bf16*)(ws);             // [0,32M)  live until gi done
    bf16* WHHB  = (bf16*)(ws);             // 6M, cast AFTER gi (overlaps CAT)
    bf16* GI    = (bf16*)(ws + 32 * MB);   // [32,80M)
    bf16* GH    = (bf16*)(ws + 80 * MB);   // [80,128M) written late
    // temporaries inside the GH region (dead before GH is written):
    bf16* WVB   = (bf16*)(ws + 80 * MB);   // 2M
    bf16* WOPB  = (bf16*)(ws + 82 * MB);   // 2M
    bf16* WIHB  = (bf16*)(ws + 84 * MB);   // 6M
    bf16* WIPT  = (bf16*)(ws + 90 * MB);   // 2M
    bf16* T1T   = (bf16*)(ws + 92 * MB);   // 2M
    bf16* T2T   = (bf16*)(ws + 94 * MB);   // 2M
    bf16* WFGB  = (bf16*)(ws + 96 * MB);   // 4M
    float* T1B  = (float*)(ws + 100 * MB);
    float* T2B  = (float*)(ws + 100 * MB + 8192);
    float* T3B  = (float*)(ws + 100 * MB + 16384);
    bf16* GATED = (bf16*)(ws + 128 * MB);  // [128,144M); becomes UPD in place
    bf16* WCOMB = (bf16*)(ws + 144 * MB);  // [144,150M)
    bf16* WOGB  = (bf16*)(ws + 150 * MB);  // [150,152M)

    const int M = B_ROWS;
    dim3 blk(256);

    // 1. activations -> bf16 concat
    build_cat_k<<<dim3((M * 2048 / 4) / 256), blk, 0, stream>>>(prev, input, CAT);
    // 2. all front weight casts in one launch
    cast_weights_k<<<dim3(8192), blk, 0, stream>>>(
        in_proj_w + 2048 * 1024, out_proj_w, gih_w, fg_w, og_w,
        WVB, WOPB, WIHB, WFGB, WOGB);
    // 3. Wip^T (bf16)
    transpose_cast_k<<<dim3(32, 32), blk, 0, stream>>>(ip_w, WIPT, 1024, 1024);
    // 4. bias chain (fp32, exact)
    gemv_k<<<dim3(256), blk, 0, stream>>>(in_proj_w + 2048 * 1024, ip_b, in_proj_b + 2048, T1B, 1024);
    gemv_k<<<dim3(256), blk, 0, stream>>>(out_proj_w, T1B, out_proj_b, T2B, 1024);
    gemv_k<<<dim3(768), blk, 0, stream>>>(gih_w, T2B, gih_b, T3B, 1024);
    // 5-7. weight composition: Wcomb = Wih @ Wop @ Wv @ Wip
    gemm64_k<<<dim3(128), blk, 0, stream>>>(WVB, 1024, WIPT, 1024, nullptr,
        1024, 1024, 3, T1T, nullptr, nullptr, nullptr, 1024, 16);  // (Wv@Wip)^T
    gemm64_k<<<dim3(128), blk, 0, stream>>>(WOPB, 1024, T1T, 1024, nullptr,
        1024, 1024, 3, T2T, nullptr, nullptr, nullptr, 1024, 16);  // (Wop@..)^T
    gemm64_k<<<dim3(384), blk, 0, stream>>>(WIHB, 1024, T2T, 1024, nullptr,
        1024, 1024, 0, WCOMB, nullptr, nullptr, nullptr, 0, 48);   // Wcomb
    // 8. gated = prev * sigmoid(cat @ Wfg^T + bfg)
    gemm128_k<<<dim3(512), blk, 0, stream>>>(CAT, 2048, WFGB, 2048,
        fg_b, 1024, 2048, 1, GATED, nullptr, prev, nullptr, 0, 64);
    // 9. gi = x @ Wcomb^T + bcomb                    [256x128 tile]
    gemm256x128_k<<<dim3(768), blk, 0, stream>>>(CAT + 1024, 2048, WCOMB,
        1024, T3B, 3072, 1024, GI, 32);
    // 10. Whh cast (CAT now dead)
    cast_f32_bf16_k<<<dim3(3072), blk, 0, stream>>>(ghh_w, WHHB, 3072 * 1024 / 4);
    // 11. gh = gated @ Whh^T + bhh                   [256x128 tile]
    gemm256x128_k<<<dim3(768), blk, 0, stream>>>(GATED, 1024, WHHB,
        1024, ghh_b, 3072, 1024, GH, 32);
    // 12. GRU combine (in place: GATED becomes UPD)
    gru_combine_k<<<dim3(M * 1024 / 8 / 256), blk, 0, stream>>>(GI, GH, GATED);
    // 13. out = upd * sigmoid(upd @ Wog^T + bog)
    gemm128_k<<<dim3(512), blk, 0, stream>>>(GATED, 1024, WOGB, 1024,
        og_b, 1024, 1024, 2, nullptr, out, nullptr, GATED, 0, 64);
    // 14. attention weights == 1.0
    fill_ones_k<<<dim3(32), blk, 0, stream>>>(out + (size_t)M * 1024, M);
}

// Round 6
// 467.781 us; speedup vs baseline: 1.1368x; 1.0499x over previous
//
#include <hip/hip_runtime.h>
#include <cstdint>
#include <cstddef>

// ---------------------------------------------------------------------------
// DynamicMemoryCell on MI355X (gfx950) — round 10
//
// Math: softmax over 1 key == 1 -> attn == v; q/k/pm dead.
// Linear chain pi->v->ctx->gi collapsed: Wcomb = Wih@Wop@Wv@Wip (per call).
//
// Round-10 vs round-9: round-9 confirmed the 256x128 tile (gi/gh 90->67us,
// MfmaUtil 31%, WRITE amp gone). fg/og were still on the 128^2 kernel with
// scattered epilogues (fg: 510 TF, WRITE 35.5MB for 16MB out; og: ~2x f32
// write amp).
//   * fg (epi1) and og (epi2) moved to gemm256x128_k. N=1024 -> grid 256
//     blocks = exactly 1/CU. Coalesced epilogues via f32 LDS C-stage in two
//     128-row half-passes (128x132 f32 = 67.5KB <= 72KB LDS); sigmoid still
//     computed from fp32 val -> numerics identical to round-9.
//   * race fix: block barrier between the tail vmcnt(0) drain and LDS
//     reuse as C-stage (per-wave vmcnt doesn't order OTHER waves'
//     in-flight global_load_lds writes).
//   * gemm128_k removed (dead); gemm64_k kept for weight composition.
// ---------------------------------------------------------------------------

typedef __bf16 bf16;
typedef bf16 bf16x4 __attribute__((ext_vector_type(4)));
typedef bf16 bf16x8 __attribute__((ext_vector_type(8)));
typedef float f32x4 __attribute__((ext_vector_type(4)));

#define B_ROWS 8192

__device__ __forceinline__ float sigmoid_f(float x) {
    return 1.0f / (1.0f + __expf(-x));
}
__device__ __forceinline__ float tanh_f(float x) {
    return 1.0f - 2.0f / (__expf(2.0f * x) + 1.0f);
}

// ---------------------------------------------------------------------------
// 256x128 triple-buffered GEMM: C[M,N] = A[M,K] @ W[N,K]^T + bias.
// 4 waves (2M x 2N), wave tile 128x64, acc[8][4] f32x4.
// LDS: sA 3x256x32 + sB 3x128x32 bf16 = 72 KiB; reused as C-stage in the
// epilogue (epi0: 256x136 bf16 = 68KB; epi1/2: 128x132 f32 = 67.5KB halves).
// Counted vmcnt: 6 loads/stage; steady state 12 outstanding, wait vmcnt(6).
// epi 0: out_bf = bf16(val)                            (gi / gh)
// epi 1: out_bf = bf16(aux_f32 * sigmoid(val))         (forget gate)
// epi 2: out_f32 = float(aux_bf) * sigmoid(val)        (output gate)
// ---------------------------------------------------------------------------
__global__ __launch_bounds__(256, 2) void gemm256x128_k(
    const bf16* __restrict__ A, int lda,
    const bf16* __restrict__ W, int ldw,
    const float* __restrict__ bias, int N, int K, int epi,
    bf16* __restrict__ out_bf, float* __restrict__ out_f32,
    const float* __restrict__ aux_f32, const bf16* __restrict__ aux_bf,
    int nby)
{
    __shared__ bf16 lds[36864];          // 72 KiB
    bf16* sA = lds;                       // 3 x 256 x 32
    bf16* sB = lds + 3 * 256 * 32;        // 3 x 128 x 32

    const int tid  = threadIdx.x;
    const int lane = tid & 63;
    const int wave = tid >> 6;
    const int wm   = wave >> 1;          // 0..1 (M half: 128 rows)
    const int wn   = wave & 1;           // 0..1 (N half: 64 cols)
    const int lrow = lane & 15;
    const int lq   = lane >> 4;

    const int by   = blockIdx.x % nby;   // y-fastest: co-residents share W
    const int bx   = blockIdx.x / nby;
    const int brow = by * 256;
    const int bcol = bx * 128;

    f32x4 acc[8][4];
#pragma unroll
    for (int i = 0; i < 8; ++i)
#pragma unroll
        for (int j = 0; j < 4; ++j) {
            f32x4 z = {0.0f, 0.0f, 0.0f, 0.0f};
            acc[i][j] = z;
        }

    // stage one BK=32 tile: A 4 insts (256 rows), B 2 insts (128 rows).
    // LDS dest linear (rule #21); swizzle via permuted GLOBAL source col.
    auto stage = [&](bf16* dA, bf16* dB, int k0) {
#pragma unroll
        for (int i = 0; i < 4; ++i) {
            const int s   = tid + i * 256;
            const int row = s >> 2;
            const int col = (((s & 3) ^ ((s >> 3) & 3)) << 3);
            const bf16* gp = A + (size_t)(brow + row) * lda + (k0 + col);
            __builtin_amdgcn_global_load_lds(
                (const __attribute__((address_space(1))) void*)gp,
                (__attribute__((address_space(3))) void*)(&dA[s * 8]),
                16, 0, 0);
        }
#pragma unroll
        for (int i = 0; i < 2; ++i) {
            const int s   = tid + i * 256;
            const int row = s >> 2;
            const int col = (((s & 3) ^ ((s >> 3) & 3)) << 3);
            const bf16* gp = W + (size_t)(bcol + row) * ldw + (k0 + col);
            __builtin_amdgcn_global_load_lds(
                (const __attribute__((address_space(1))) void*)gp,
                (__attribute__((address_space(3))) void*)(&dB[s * 8]),
                16, 0, 0);
        }
    };

    const int NT = K >> 5;

    bf16* a0 = sA;                bf16* b0 = sB;
    bf16* a1 = sA + 256 * 32;     bf16* b1 = sB + 128 * 32;
    bf16* a2 = sA + 2 * 256 * 32; bf16* b2 = sB + 2 * 128 * 32;

    stage(a0, b0, 0);
    stage(a1, b1, NT > 1 ? 32 : 0);
    asm volatile("s_waitcnt vmcnt(6)" ::: "memory");  // tile 0 landed
    __builtin_amdgcn_s_barrier();
    __builtin_amdgcn_sched_barrier(0);

    for (int kt = 0; kt < NT; ++kt) {
        bf16x8 av[8], bv[4];
#pragma unroll
        for (int i = 0; i < 8; ++i) {
            const int r = wm * 128 + i * 16 + lrow;
            av[i] = *(const bf16x8*)&a0[r * 32 + ((lq ^ ((r >> 1) & 3)) << 3)];
        }
#pragma unroll
        for (int j = 0; j < 4; ++j) {
            const int r = wn * 64 + j * 16 + lrow;
            bv[j] = *(const bf16x8*)&b0[r * 32 + ((lq ^ ((r >> 1) & 3)) << 3)];
        }

        // tile kt+2 into the free buffer (tail re-stages: uniform FIFO)
        const int kn = (kt + 2 < NT ? kt + 2 : NT - 1) << 5;
        stage(a2, b2, kn);

#pragma unroll
        for (int i = 0; i < 8; ++i)
#pragma unroll
            for (int j = 0; j < 4; ++j)
                acc[i][j] = __builtin_amdgcn_mfma_f32_16x16x32_bf16(
                    av[i], bv[j], acc[i][j], 0, 0, 0);

        __builtin_amdgcn_sched_barrier(0);
        asm volatile("s_waitcnt vmcnt(6)" ::: "memory"); // kt+1 landed
        __builtin_amdgcn_s_barrier();
        __builtin_amdgcn_sched_barrier(0);

        bf16* ta = a0; a0 = a1; a1 = a2; a2 = ta;
        bf16* tb = b0; b0 = b1; b1 = b2; b2 = tb;
    }

    // drain redundant tail stages; BLOCK barrier before LDS reuse (per-wave
    // vmcnt doesn't order other waves' in-flight global_load_lds writes)
    asm volatile("s_waitcnt vmcnt(0)" ::: "memory");
    __syncthreads();

    if (epi == 0) {
        // ---- bf16 C-stage (stride 136: 2-way-max), coalesced b128 flush --
        bf16* cb = lds;
#pragma unroll
        for (int j = 0; j < 4; ++j) {
            const int col = wn * 64 + j * 16 + lrow;
            const float bj = bias[bcol + col];
#pragma unroll
            for (int i = 0; i < 8; ++i) {
                const int rowb = wm * 128 + i * 16 + lq * 4;
#pragma unroll
                for (int r = 0; r < 4; ++r)
                    cb[(rowb + r) * 136 + col] = (bf16)(acc[i][j][r] + bj);
            }
        }
        __syncthreads();
#pragma unroll
        for (int p = 0; p < 16; ++p) {
            const int row = p * 16 + (tid >> 4);
            const int col = (tid & 15) * 8;
            bf16x8 v = *(const bf16x8*)&cb[row * 136 + col];
            *(bf16x8*)&out_bf[(size_t)(brow + row) * N + bcol + col] = v;
        }
    } else {
        // ---- f32 C-stage in two 128-row halves (exact sigmoid input) -----
        float* cf = (float*)lds;           // 128 x 132 f32 = 67.5 KiB
#pragma unroll
        for (int h = 0; h < 2; ++h) {
            if (wm == h) {
#pragma unroll
                for (int j = 0; j < 4; ++j) {
                    const int col = wn * 64 + j * 16 + lrow;
                    const float bj = bias[bcol + col];
#pragma unroll
                    for (int i = 0; i < 8; ++i) {
                        const int rl = i * 16 + lq * 4;
#pragma unroll
                        for (int r = 0; r < 4; ++r)
                            cf[(rl + r) * 132 + col] = acc[i][j][r] + bj;
                    }
                }
            }
            __syncthreads();
#pragma unroll
            for (int p = 0; p < 16; ++p) {
                const int idx = p * 256 + tid;
                const int row = idx >> 5;
                const int ch  = idx & 31;
                f32x4 v = *(const f32x4*)&cf[row * 132 + ch * 4];
                const int grow = brow + h * 128 + row;
                const int gcol = bcol + ch * 4;
                const size_t gidx = (size_t)grow * N + gcol;
                if (epi == 1) {
                    f32x4 a4 = *(const f32x4*)&aux_f32[gidx];
                    bf16x4 o;
#pragma unroll
                    for (int e = 0; e < 4; ++e)
                        o[e] = (bf16)(a4[e] * sigmoid_f(v[e]));
                    *(bf16x4*)&out_bf[gidx] = o;
                } else {
                    bf16x4 ab = *(const bf16x4*)&aux_bf[gidx];
                    f32x4 o;
#pragma unroll
                    for (int e = 0; e < 4; ++e)
                        o[e] = (float)ab[e] * sigmoid_f(v[e]);
                    *(f32x4*)&out_f32[gidx] = o;
                }
            }
            __syncthreads();
        }
    }
}

// ---------------------------------------------------------------------------
// Triple-buffered GEMM core (small weight-composition GEMMs): BM x 128 tile.
// epi 0: out_bf = bf16(val);  epi 3: out_bf[gcol*tld + grow] (transposed)
// ---------------------------------------------------------------------------
template <int BM>
__device__ __forceinline__ void gemm_core_tb(
    bf16* sA, bf16* sB,
    const bf16* __restrict__ A, int lda,
    const bf16* __restrict__ W, int ldw,
    const float* __restrict__ bias,
    int N, int K, int brow, int bcol, int epi,
    bf16* __restrict__ out_bf, int tld)
{
    constexpr int AI = BM / 32;
    const int tid  = threadIdx.x;
    const int lane = tid & 63;
    const int wave = tid >> 6;
    const int wr   = (wave & 1) * (BM / 2);
    const int wc   = (wave >> 1) * 64;
    const int lrow = lane & 15;
    const int lq   = lane >> 4;

    f32x4 acc[AI][4];
#pragma unroll
    for (int i = 0; i < AI; ++i)
#pragma unroll
        for (int j = 0; j < 4; ++j) {
            f32x4 z = {0.0f, 0.0f, 0.0f, 0.0f};
            acc[i][j] = z;
        }

    auto stage = [&](bf16* dA, bf16* dB, int k0) {
#pragma unroll
        for (int i = 0; i < BM / 64; ++i) {
            const int s   = tid + i * 256;
            const int row = s >> 2;
            const int col = (((s & 3) ^ ((s >> 3) & 3)) << 3);
            const bf16* gp = A + (size_t)(brow + row) * lda + (k0 + col);
            __builtin_amdgcn_global_load_lds(
                (const __attribute__((address_space(1))) void*)gp,
                (__attribute__((address_space(3))) void*)(&dA[s * 8]),
                16, 0, 0);
        }
#pragma unroll
        for (int i = 0; i < 2; ++i) {
            const int s   = tid + i * 256;
            const int row = s >> 2;
            const int col = (((s & 3) ^ ((s >> 3) & 3)) << 3);
            const bf16* gp = W + (size_t)(bcol + row) * ldw + (k0 + col);
            __builtin_amdgcn_global_load_lds(
                (const __attribute__((address_space(1))) void*)gp,
                (__attribute__((address_space(3))) void*)(&dB[s * 8]),
                16, 0, 0);
        }
    };

#define WAIT_LPS()                                                   \
    do {                                                             \
        if constexpr (BM == 128)                                     \
            asm volatile("s_waitcnt vmcnt(4)" ::: "memory");         \
        else                                                         \
            asm volatile("s_waitcnt vmcnt(3)" ::: "memory");         \
    } while (0)

    const int NT = K >> 5;

    bf16* a0 = sA;               bf16* b0 = sB;
    bf16* a1 = sA + BM * 32;     bf16* b1 = sB + 4096;
    bf16* a2 = sA + 2 * BM * 32; bf16* b2 = sB + 2 * 4096;

    stage(a0, b0, 0);
    stage(a1, b1, NT > 1 ? 32 : 0);
    WAIT_LPS();
    __builtin_amdgcn_s_barrier();
    __builtin_amdgcn_sched_barrier(0);

    for (int kt = 0; kt < NT; ++kt) {
        bf16x8 av[AI], bv[4];
#pragma unroll
        for (int i = 0; i < AI; ++i) {
            const int r = wr + i * 16 + lrow;
            av[i] = *(const bf16x8*)&a0[r * 32 + ((lq ^ ((r >> 1) & 3)) << 3)];
        }
#pragma unroll
        for (int j = 0; j < 4; ++j) {
            const int r = wc + j * 16 + lrow;
            bv[j] = *(const bf16x8*)&b0[r * 32 + ((lq ^ ((r >> 1) & 3)) << 3)];
        }

        const int kn = (kt + 2 < NT ? kt + 2 : NT - 1) << 5;
        stage(a2, b2, kn);

#pragma unroll
        for (int i = 0; i < AI; ++i)
#pragma unroll
            for (int j = 0; j < 4; ++j)
                acc[i][j] = __builtin_amdgcn_mfma_f32_16x16x32_bf16(
                    av[i], bv[j], acc[i][j], 0, 0, 0);

        __builtin_amdgcn_sched_barrier(0);
        WAIT_LPS();
        __builtin_amdgcn_s_barrier();
        __builtin_amdgcn_sched_barrier(0);

        bf16* ta = a0; a0 = a1; a1 = a2; a2 = ta;
        bf16* tb = b0; b0 = b1; b1 = b2; b2 = tb;
    }

    asm volatile("s_waitcnt vmcnt(0)" ::: "memory");
#undef WAIT_LPS

    // epilogue: C/D layout col = lane&15, row = (lane>>4)*4 + reg
#pragma unroll
    for (int j = 0; j < 4; ++j) {
        const int gcol = bcol + wc + j * 16 + lrow;
        const float bj = bias ? bias[gcol] : 0.0f;
#pragma unroll
        for (int i = 0; i < AI; ++i) {
            const int growb = brow + wr + i * 16 + lq * 4;
#pragma unroll
            for (int r = 0; r < 4; ++r) {
                const int grow = growb + r;
                const float val = acc[i][j][r] + bj;
                if (epi == 0) {
                    out_bf[(size_t)grow * N + gcol] = (bf16)val;
                } else {
                    out_bf[(size_t)gcol * tld + grow] = (bf16)val;
                }
            }
        }
    }
}

__global__ __launch_bounds__(256, 2) void gemm64_k(
    const bf16* __restrict__ A, int lda, const bf16* __restrict__ W, int ldw,
    const float* __restrict__ bias, int N, int K, int epi,
    bf16* __restrict__ out_bf, int tld, int nby)
{
    __shared__ bf16 sA[3 * 64 * 32];
    __shared__ bf16 sB[3 * 128 * 32];
    const int by = blockIdx.x % nby;
    const int bx = blockIdx.x / nby;
    gemm_core_tb<64>(sA, sB, A, lda, W, ldw, bias, N, K,
                     by * 64, bx * 128, epi, out_bf, tld);
}

// ---------------------------------------------------------------------------
// Elementwise / small helpers
// ---------------------------------------------------------------------------

__global__ void cast_weights_k(
    const float* __restrict__ wv, const float* __restrict__ wop,
    const float* __restrict__ wih, const float* __restrict__ wfg,
    const float* __restrict__ wog,
    bf16* __restrict__ dv, bf16* __restrict__ dop, bf16* __restrict__ dih,
    bf16* __restrict__ dfg, bf16* __restrict__ dog)
{
    int c = blockIdx.x * 256 + threadIdx.x;  // [0, 2097152)
    const float* s;
    bf16* d;
    int o;
    if (c < 262144)        { s = wv;  d = dv;  o = c; }
    else if (c < 524288)   { s = wop; d = dop; o = c - 262144; }
    else if (c < 1310720)  { s = wih; d = dih; o = c - 524288; }
    else if (c < 1835008)  { s = wfg; d = dfg; o = c - 1310720; }
    else                   { s = wog; d = dog; o = c - 1835008; }
    f32x4 v = ((const f32x4*)s)[o];
    bf16x4 t = {(bf16)v[0], (bf16)v[1], (bf16)v[2], (bf16)v[3]};
    ((bf16x4*)d)[o] = t;
}

__global__ void cast_f32_bf16_k(const float* __restrict__ src,
                                bf16* __restrict__ dst, int n4) {
    int i = blockIdx.x * 256 + threadIdx.x;
    if (i >= n4) return;
    f32x4 v = ((const f32x4*)src)[i];
    bf16x4 o = {(bf16)v[0], (bf16)v[1], (bf16)v[2], (bf16)v[3]};
    ((bf16x4*)dst)[i] = o;
}

__global__ void build_cat_k(const float* __restrict__ mem,
                            const float* __restrict__ inp,
                            bf16* __restrict__ cat) {
    int i = blockIdx.x * 256 + threadIdx.x;
    int row = i >> 9;
    int c4  = i & 511;
    f32x4 v;
    if (c4 < 256)
        v = ((const f32x4*)mem)[(size_t)row * 256 + c4];
    else
        v = ((const f32x4*)inp)[(size_t)row * 256 + (c4 - 256)];
    bf16x4 o = {(bf16)v[0], (bf16)v[1], (bf16)v[2], (bf16)v[3]};
    ((bf16x4*)cat)[i] = o;
}

// src [R,C] f32  ->  dst [C,R] bf16
__global__ void transpose_cast_k(const float* __restrict__ src,
                                 bf16* __restrict__ dst, int R, int C) {
    __shared__ float t[32][33];
    int bx = blockIdx.x * 32;
    int by = blockIdx.y * 32;
    int tx = threadIdx.x & 31, ty = threadIdx.x >> 5;
#pragma unroll
    for (int i = 0; i < 32; i += 8)
        t[ty + i][tx] = src[(size_t)(by + ty + i) * C + bx + tx];
    __syncthreads();
#pragma unroll
    for (int i = 0; i < 32; i += 8)
        dst[(size_t)(bx + ty + i) * R + by + tx] = (bf16)t[tx][ty + i];
}

// y[n] = b[n] + sum_k W[n,k] * x[k]   (fp32; one wave per output row)
__global__ void gemv_k(const float* __restrict__ W, const float* __restrict__ x,
                       const float* __restrict__ b, float* __restrict__ y,
                       int K) {
    int n    = blockIdx.x * 4 + (threadIdx.x >> 6);
    int lane = threadIdx.x & 63;
    const float* row = W + (size_t)n * K;
    float s = 0.0f;
    for (int k = lane * 4; k < K; k += 256) {
        f32x4 w = *(const f32x4*)(row + k);
        f32x4 xv = *(const f32x4*)(x + k);
        s += w[0] * xv[0] + w[1] * xv[1] + w[2] * xv[2] + w[3] * xv[3];
    }
#pragma unroll
    for (int off = 32; off; off >>= 1) s += __shfl_down(s, off);
    if (lane == 0) y[n] = s + b[n];
}

// GRU combine, in place: upd (=gated buffer) = (1-z)*n + z*gated
__global__ void gru_combine_k(const bf16* __restrict__ gi,
                              const bf16* __restrict__ gh,
                              bf16* __restrict__ gated) {
    int i   = blockIdx.x * 256 + threadIdx.x;
    int row = i >> 7;
    int c   = (i & 127) << 3;
    size_t b3 = (size_t)row * 3072 + c;
    size_t b1 = (size_t)row * 1024 + c;
    bf16x8 gir = *(const bf16x8*)(gi + b3);
    bf16x8 giz = *(const bf16x8*)(gi + b3 + 1024);
    bf16x8 gin = *(const bf16x8*)(gi + b3 + 2048);
    bf16x8 ghr = *(const bf16x8*)(gh + b3);
    bf16x8 ghz = *(const bf16x8*)(gh + b3 + 1024);
    bf16x8 ghn = *(const bf16x8*)(gh + b3 + 2048);
    bf16x8 g   = *(const bf16x8*)(gated + b1);
    bf16x8 o;
#pragma unroll
    for (int e = 0; e < 8; ++e) {
        float r = sigmoid_f((float)gir[e] + (float)ghr[e]);
        float z = sigmoid_f((float)giz[e] + (float)ghz[e]);
        float n = tanh_f((float)gin[e] + r * (float)ghn[e]);
        o[e] = (bf16)((1.0f - z) * n + z * (float)g[e]);
    }
    *(bf16x8*)(gated + b1) = o;
}

__global__ void fill_ones_k(float* __restrict__ p, int n) {
    int i = blockIdx.x * 256 + threadIdx.x;
    if (i < n) p[i] = 1.0f;
}

// ---------------------------------------------------------------------------
// Launch
// ---------------------------------------------------------------------------
extern "C" void kernel_launch(void* const* d_in, const int* in_sizes, int n_in,
                              void* d_out, int out_size, void* d_ws,
                              size_t ws_size, hipStream_t stream) {
    const float* input      = (const float*)d_in[0];
    const float* prev       = (const float*)d_in[1];
    const float* in_proj_w  = (const float*)d_in[2];
    const float* in_proj_b  = (const float*)d_in[3];
    const float* out_proj_w = (const float*)d_in[4];
    const float* out_proj_b = (const float*)d_in[5];
    const float* ip_w       = (const float*)d_in[6];
    const float* ip_b       = (const float*)d_in[7];
    // d_in[8]/d_in[9] (mp_w/mp_b) dead: softmax over one key == 1
    const float* fg_w  = (const float*)d_in[10];
    const float* fg_b  = (const float*)d_in[11];
    const float* og_w  = (const float*)d_in[12];
    const float* og_b  = (const float*)d_in[13];
    const float* gih_w = (const float*)d_in[14];
    const float* gih_b = (const float*)d_in[15];
    const float* ghh_w = (const float*)d_in[16];
    const float* ghh_b = (const float*)d_in[17];
    float* out = (float*)d_out;

    // ---- workspace layout (152 MiB, overlaps respect dependency order)
    char* ws = (char*)d_ws;
    const size_t MB = 1024 * 1024;
    bf16* CAT   = (bf16*)(ws);             // [0,32M)  live until gi done
    bf16* WHHB  = (bf16*)(ws);             // 6M, cast AFTER gi (overlaps CAT)
    bf16* GI    = (bf16*)(ws + 32 * MB);   // [32,80M)
    bf16* GH    = (bf16*)(ws + 80 * MB);   // [80,128M) written late
    // temporaries inside the GH region (dead before GH is written):
    bf16* WVB   = (bf16*)(ws + 80 * MB);   // 2M
    bf16* WOPB  = (bf16*)(ws + 82 * MB);   // 2M
    bf16* WIHB  = (bf16*)(ws + 84 * MB);   // 6M
    bf16* WIPT  = (bf16*)(ws + 90 * MB);   // 2M
    bf16* T1T   = (bf16*)(ws + 92 * MB);   // 2M
    bf16* T2T   = (bf16*)(ws + 94 * MB);   // 2M
    bf16* WFGB  = (bf16*)(ws + 96 * MB);   // 4M
    float* T1B  = (float*)(ws + 100 * MB);
    float* T2B  = (float*)(ws + 100 * MB + 8192);
    float* T3B  = (float*)(ws + 100 * MB + 16384);
    bf16* GATED = (bf16*)(ws + 128 * MB);  // [128,144M); becomes UPD in place
    bf16* WCOMB = (bf16*)(ws + 144 * MB);  // [144,150M)
    bf16* WOGB  = (bf16*)(ws + 150 * MB);  // [150,152M)

    const int M = B_ROWS;
    dim3 blk(256);

    // 1. activations -> bf16 concat
    build_cat_k<<<dim3((M * 2048 / 4) / 256), blk, 0, stream>>>(prev, input, CAT);
    // 2. all front weight casts in one launch
    cast_weights_k<<<dim3(8192), blk, 0, stream>>>(
        in_proj_w + 2048 * 1024, out_proj_w, gih_w, fg_w, og_w,
        WVB, WOPB, WIHB, WFGB, WOGB);
    // 3. Wip^T (bf16)
    transpose_cast_k<<<dim3(32, 32), blk, 0, stream>>>(ip_w, WIPT, 1024, 1024);
    // 4. bias chain (fp32, exact)
    gemv_k<<<dim3(256), blk, 0, stream>>>(in_proj_w + 2048 * 1024, ip_b, in_proj_b + 2048, T1B, 1024);
    gemv_k<<<dim3(256), blk, 0, stream>>>(out_proj_w, T1B, out_proj_b, T2B, 1024);
    gemv_k<<<dim3(768), blk, 0, stream>>>(gih_w, T2B, gih_b, T3B, 1024);
    // 5-7. weight composition: Wcomb = Wih @ Wop @ Wv @ Wip
    gemm64_k<<<dim3(128), blk, 0, stream>>>(WVB, 1024, WIPT, 1024, nullptr,
        1024, 1024, 3, T1T, 1024, 16);  // (Wv@Wip)^T
    gemm64_k<<<dim3(128), blk, 0, stream>>>(WOPB, 1024, T1T, 1024, nullptr,
        1024, 1024, 3, T2T, 1024, 16);  // (Wop@..)^T
    gemm64_k<<<dim3(384), blk, 0, stream>>>(WIHB, 1024, T2T, 1024, nullptr,
        1024, 1024, 0, WCOMB, 0, 48);   // Wcomb
    // 8. gated = prev * sigmoid(cat @ Wfg^T + bfg)   [256x128, epi1]
    gemm256x128_k<<<dim3(256), blk, 0, stream>>>(CAT, 2048, WFGB, 2048,
        fg_b, 1024, 2048, 1, GATED, nullptr, prev, nullptr, 32);
    // 9. gi = x @ Wcomb^T + bcomb                    [256x128, epi0]
    gemm256x128_k<<<dim3(768), blk, 0, stream>>>(CAT + 1024, 2048, WCOMB,
        1024, T3B, 3072, 1024, 0, GI, nullptr, nullptr, nullptr, 32);
    // 10. Whh cast (CAT now dead)
    cast_f32_bf16_k<<<dim3(3072), blk, 0, stream>>>(ghh_w, WHHB, 3072 * 1024 / 4);
    // 11. gh = gated @ Whh^T + bhh                   [256x128, epi0]
    gemm256x128_k<<<dim3(768), blk, 0, stream>>>(GATED, 1024, WHHB,
        1024, ghh_b, 3072, 1024, 0, GH, nullptr, nullptr, nullptr, 32);
    // 12. GRU combine (in place: GATED becomes UPD)
    gru_combine_k<<<dim3(M * 1024 / 8 / 256), blk, 0, stream>>>(GI, GH, GATED);
    // 13. out = upd * sigmoid(upd @ Wog^T + bog)     [256x128, epi2]
    gemm256x128_k<<<dim3(256), blk, 0, stream>>>(GATED, 1024, WOGB, 1024,
        og_b, 1024, 1024, 2, nullptr, out, nullptr, GATED, 32);
    // 14. attention weights == 1.0
    fill_ones_k<<<dim3(32), blk, 0, stream>>>(out + (size_t)M * 1024, M);
}

// Round 7
// 455.201 us; speedup vs baseline: 1.1682x; 1.0276x over previous
//
#include <hip/hip_runtime.h>
#include <cstdint>
#include <cstddef>

// ---------------------------------------------------------------------------
// DynamicMemoryCell on MI355X (gfx950) — round 11
//
// Math: softmax over 1 key == 1 -> attn == v; q/k/pm dead.
// Linear chain pi->v->ctx->gi collapsed: Wcomb = Wih@Wop@Wv@Wip (per call).
// GRU algebra: r = sig(gi_r+gh_r), z = sig(gi_z+gh_z) use only SUMS ->
// compute Grz = [x,gated] @ [Wcomb_rz; Whh_rz]^T as ONE two-phase-K GEMM
// (pointer swap mid-K-loop, no weight prep). Only n needs gi_n, gh_n
// separately; the combine fuses into the gh_n GEMM's epilogue.
//
// Round-11 vs round-10 (468us; kernel-sum ~290 -> ~175us launch/gap + 26us
// gru_combine round-trip were the top residuals):
//   * gru_combine_k ELIMINATED (fused into g3_k epilogue); GI/GH buffers
//     (96MB write + 112MB read) replaced by GRZ+GNI (64MB write, 80MB read).
//   * ONE segmented prep kernel: cat-build + 6 weight casts (incl Whh —
//     new non-overlapping workspace layout) + Wip transpose + ones-fill.
//   * fg + gi_n merged into one 512-block launch (fg gains 2 blocks/CU).
//   * Launches 15 -> 10.
// GEMM core (g256_core) = round-10's verified 256x128 triple-buffered
// counted-vmcnt(6) structure, + two-phase-K + bias2 + combine epilogue.
// ---------------------------------------------------------------------------

typedef __bf16 bf16;
typedef bf16 bf16x4 __attribute__((ext_vector_type(4)));
typedef bf16 bf16x8 __attribute__((ext_vector_type(8)));
typedef float f32x4 __attribute__((ext_vector_type(4)));

#define B_ROWS 8192

__device__ __forceinline__ float sigmoid_f(float x) {
    return 1.0f / (1.0f + __expf(-x));
}
__device__ __forceinline__ float tanh_f(float x) {
    return 1.0f - 2.0f / (__expf(2.0f * x) + 1.0f);
}

// ---------------------------------------------------------------------------
// 256x128 triple-buffered GEMM core. 4 waves (2M x 2N), wave tile 128x64,
// acc[8][4] f32x4. LDS: sA 3x256x32 + sB 3x128x32 bf16 = 72 KiB; reused as
// C-stage in the epilogue. Counted vmcnt(6): one stage (6 loads) in flight
// across each barrier. Two K-phases: tiles [0,nt1) from A1/W1, [nt1,nt1+nt2)
// from A2/W2 — accumulators carry across the switch (computes A1@W1^T+A2@W2^T).
// EPI 0: out_bf = bf16(val)            val = acc + bias1 [+ bias2]
// EPI 1: out_bf = bf16(aux_f32 * sigmoid(val))            (forget gate)
// EPI 2: out_f32 = float(aux_bf) * sigmoid(val)           (output gate)
// EPI 4: GRU combine: val = gh_n; r,z from GRZ, gi_n from GNI, mem from GAT:
//        upd = (1-sig(z))*tanh(gi_n + sig(r)*val) + sig(z)*mem -> out_bf
// ---------------------------------------------------------------------------
template <int EPI>
__device__ __forceinline__ void g256_core(
    bf16* lds,
    const bf16* A1, int lda1, const bf16* W1, int ldw1, int nt1,
    const bf16* A2, int lda2, const bf16* W2, int ldw2, int nt2,
    const float* bias1, const float* bias2,
    int N, int brow, int bcol,
    bf16* out_bf, float* out_f32,
    const float* aux_f32, const bf16* aux_bf,
    const bf16* grz, const bf16* gni, const bf16* gat)
{
    bf16* sA = lds;                       // 3 x 256 x 32
    bf16* sB = lds + 3 * 256 * 32;        // 3 x 128 x 32

    const int tid  = threadIdx.x;
    const int lane = tid & 63;
    const int wave = tid >> 6;
    const int wm   = wave >> 1;          // M half (128 rows)
    const int wn   = wave & 1;           // N half (64 cols)
    const int lrow = lane & 15;
    const int lq   = lane >> 4;

    f32x4 acc[8][4];
#pragma unroll
    for (int i = 0; i < 8; ++i)
#pragma unroll
        for (int j = 0; j < 4; ++j) {
            f32x4 z = {0.0f, 0.0f, 0.0f, 0.0f};
            acc[i][j] = z;
        }

    // stage K-tile kt: A 4 insts (256 rows), B 2 insts (128 rows). LDS dest
    // linear (rule #21); swizzle via permuted GLOBAL source col.
    auto stage = [&](bf16* dA, bf16* dB, int kt) {
        const bf16* Ab; int lda; const bf16* Wb; int ldw; int k0;
        if (kt < nt1) { Ab = A1; lda = lda1; Wb = W1; ldw = ldw1; k0 = kt << 5; }
        else          { Ab = A2; lda = lda2; Wb = W2; ldw = ldw2; k0 = (kt - nt1) << 5; }
#pragma unroll
        for (int i = 0; i < 4; ++i) {
            const int s   = tid + i * 256;
            const int row = s >> 2;
            const int col = (((s & 3) ^ ((s >> 3) & 3)) << 3);
            const bf16* gp = Ab + (size_t)(brow + row) * lda + (k0 + col);
            __builtin_amdgcn_global_load_lds(
                (const __attribute__((address_space(1))) void*)gp,
                (__attribute__((address_space(3))) void*)(&dA[s * 8]),
                16, 0, 0);
        }
#pragma unroll
        for (int i = 0; i < 2; ++i) {
            const int s   = tid + i * 256;
            const int row = s >> 2;
            const int col = (((s & 3) ^ ((s >> 3) & 3)) << 3);
            const bf16* gp = Wb + (size_t)(bcol + row) * ldw + (k0 + col);
            __builtin_amdgcn_global_load_lds(
                (const __attribute__((address_space(1))) void*)gp,
                (__attribute__((address_space(3))) void*)(&dB[s * 8]),
                16, 0, 0);
        }
    };

    const int NT = nt1 + nt2;

    bf16* a0 = sA;           bf16* b0 = sB;
    bf16* a1 = sA + 8192;    bf16* b1 = sB + 4096;
    bf16* a2 = sA + 16384;   bf16* b2 = sB + 8192;

    stage(a0, b0, 0);
    stage(a1, b1, 1);
    asm volatile("s_waitcnt vmcnt(6)" ::: "memory");  // tile 0 landed
    __builtin_amdgcn_s_barrier();
    __builtin_amdgcn_sched_barrier(0);

    for (int kt = 0; kt < NT; ++kt) {
        bf16x8 av[8], bv[4];
#pragma unroll
        for (int i = 0; i < 8; ++i) {
            const int r = wm * 128 + i * 16 + lrow;
            av[i] = *(const bf16x8*)&a0[r * 32 + ((lq ^ ((r >> 1) & 3)) << 3)];
        }
#pragma unroll
        for (int j = 0; j < 4; ++j) {
            const int r = wn * 64 + j * 16 + lrow;
            bv[j] = *(const bf16x8*)&b0[r * 32 + ((lq ^ ((r >> 1) & 3)) << 3)];
        }

        // tile kt+2 into the free buffer (tail re-stages: uniform FIFO)
        stage(a2, b2, kt + 2 < NT ? kt + 2 : NT - 1);

#pragma unroll
        for (int i = 0; i < 8; ++i)
#pragma unroll
            for (int j = 0; j < 4; ++j)
                acc[i][j] = __builtin_amdgcn_mfma_f32_16x16x32_bf16(
                    av[i], bv[j], acc[i][j], 0, 0, 0);

        __builtin_amdgcn_sched_barrier(0);
        asm volatile("s_waitcnt vmcnt(6)" ::: "memory"); // kt+1 landed
        __builtin_amdgcn_s_barrier();
        __builtin_amdgcn_sched_barrier(0);

        bf16* ta = a0; a0 = a1; a1 = a2; a2 = ta;
        bf16* tb = b0; b0 = b1; b1 = b2; b2 = tb;
    }

    // drain redundant tail stages; BLOCK barrier before LDS reuse (per-wave
    // vmcnt doesn't order other waves' in-flight global_load_lds writes)
    asm volatile("s_waitcnt vmcnt(0)" ::: "memory");
    __syncthreads();

    if constexpr (EPI == 0) {
        // ---- bf16 C-stage (stride 136: 2-way-max), coalesced b128 flush --
        bf16* cb = lds;
#pragma unroll
        for (int j = 0; j < 4; ++j) {
            const int col = wn * 64 + j * 16 + lrow;
            float bj = bias1[bcol + col];
            if (bias2) bj += bias2[bcol + col];
#pragma unroll
            for (int i = 0; i < 8; ++i) {
                const int rowb = wm * 128 + i * 16 + lq * 4;
#pragma unroll
                for (int r = 0; r < 4; ++r)
                    cb[(rowb + r) * 136 + col] = (bf16)(acc[i][j][r] + bj);
            }
        }
        __syncthreads();
#pragma unroll
        for (int p = 0; p < 16; ++p) {
            const int row = p * 16 + (tid >> 4);
            const int col = (tid & 15) * 8;
            bf16x8 v = *(const bf16x8*)&cb[row * 136 + col];
            *(bf16x8*)&out_bf[(size_t)(brow + row) * N + bcol + col] = v;
        }
    } else {
        // ---- f32 C-stage in two 128-row halves (exact activation input) --
        float* cf = (float*)lds;           // 128 x 132 f32 = 67.5 KiB
#pragma unroll
        for (int h = 0; h < 2; ++h) {
            if (wm == h) {
#pragma unroll
                for (int j = 0; j < 4; ++j) {
                    const int col = wn * 64 + j * 16 + lrow;
                    const float bj = bias1[bcol + col];
#pragma unroll
                    for (int i = 0; i < 8; ++i) {
                        const int rl = i * 16 + lq * 4;
#pragma unroll
                        for (int r = 0; r < 4; ++r)
                            cf[(rl + r) * 132 + col] = acc[i][j][r] + bj;
                    }
                }
            }
            __syncthreads();
#pragma unroll
            for (int p = 0; p < 16; ++p) {
                const int idx = p * 256 + tid;
                const int row = idx >> 5;
                const int ch  = idx & 31;
                f32x4 v = *(const f32x4*)&cf[row * 132 + ch * 4];
                const int grow = brow + h * 128 + row;
                const int gcol = bcol + ch * 4;
                const size_t gidx = (size_t)grow * N + gcol;
                if constexpr (EPI == 1) {
                    f32x4 a4 = *(const f32x4*)&aux_f32[gidx];
                    bf16x4 o;
#pragma unroll
                    for (int e = 0; e < 4; ++e)
                        o[e] = (bf16)(a4[e] * sigmoid_f(v[e]));
                    *(bf16x4*)&out_bf[gidx] = o;
                } else if constexpr (EPI == 2) {
                    bf16x4 ab = *(const bf16x4*)&aux_bf[gidx];
                    f32x4 o;
#pragma unroll
                    for (int e = 0; e < 4; ++e)
                        o[e] = (float)ab[e] * sigmoid_f(v[e]);
                    *(f32x4*)&out_f32[gidx] = o;
                } else {
                    // EPI == 4: GRU combine. v = gh_n (f32). N == 1024.
                    const bf16* pr = grz + (size_t)grow * 2048 + gcol;
                    bf16x4 rr = *(const bf16x4*)pr;          // r sums
                    bf16x4 zz = *(const bf16x4*)(pr + 1024); // z sums
                    bf16x4 g4 = *(const bf16x4*)&gni[gidx];  // gi_n
                    bf16x4 m4 = *(const bf16x4*)&gat[gidx];  // gated mem
                    bf16x4 o;
#pragma unroll
                    for (int e = 0; e < 4; ++e) {
                        const float r = sigmoid_f((float)rr[e]);
                        const float z = sigmoid_f((float)zz[e]);
                        const float n = tanh_f((float)g4[e] + r * v[e]);
                        o[e] = (bf16)((1.0f - z) * n + z * (float)m4[e]);
                    }
                    *(bf16x4*)&out_bf[gidx] = o;
                }
            }
            __syncthreads();
        }
    }
}

// fg (blocks 0..255, epi1, K=2048) + gi_n (blocks 256..511, epi0, K=1024):
// independent outputs, merged for fill (2 blocks/CU) and one less launch.
__global__ __launch_bounds__(256, 2) void fgg1_k(
    const bf16* __restrict__ cat, const bf16* __restrict__ wfg,
    const float* __restrict__ fg_b, const float* __restrict__ prev,
    bf16* __restrict__ gated,
    const bf16* __restrict__ wcomb_n, const float* __restrict__ bias_n,
    bf16* __restrict__ gni)
{
    __shared__ bf16 lds[36864];
    const int id = blockIdx.x;
    if (id < 256) {
        const int by = id & 31, bx = id >> 5;
        g256_core<1>(lds, cat, 2048, wfg, 2048, 64,
                     nullptr, 0, nullptr, 0, 0,
                     fg_b, nullptr, 1024, by * 256, bx * 128,
                     gated, nullptr, prev, nullptr, nullptr, nullptr, nullptr);
    } else {
        const int id2 = id - 256;
        const int by = id2 & 31, bx = id2 >> 5;
        g256_core<0>(lds, cat + 1024, 2048, wcomb_n, 1024, 32,
                     nullptr, 0, nullptr, 0, 0,
                     bias_n, nullptr, 1024, by * 256, bx * 128,
                     gni, nullptr, nullptr, nullptr, nullptr, nullptr, nullptr);
    }
}

// Grz = x @ Wcomb_rz^T + gated @ Whh_rz^T + (T3B + bhh)  [N=2048, 512 blocks]
__global__ __launch_bounds__(256, 2) void g2_k(
    const bf16* __restrict__ x, const bf16* __restrict__ wcomb,
    const bf16* __restrict__ gated, const bf16* __restrict__ whh,
    const float* __restrict__ t3b, const float* __restrict__ bhh,
    bf16* __restrict__ grz)
{
    __shared__ bf16 lds[36864];
    const int by = blockIdx.x & 31, bx = blockIdx.x >> 5;  // bx 0..15
    g256_core<0>(lds, x, 2048, wcomb, 1024, 32,
                 gated, 1024, whh, 1024, 32,
                 t3b, bhh, 2048, by * 256, bx * 128,
                 grz, nullptr, nullptr, nullptr, nullptr, nullptr, nullptr);
}

// gh_n GEMM + fused GRU combine epilogue -> UPD
__global__ __launch_bounds__(256, 2) void g3_k(
    const bf16* __restrict__ gated, const bf16* __restrict__ whh_n,
    const float* __restrict__ bhh_n,
    const bf16* __restrict__ grz, const bf16* __restrict__ gni,
    bf16* __restrict__ upd)
{
    __shared__ bf16 lds[36864];
    const int by = blockIdx.x & 31, bx = blockIdx.x >> 5;
    g256_core<4>(lds, gated, 1024, whh_n, 1024, 32,
                 nullptr, 0, nullptr, 0, 0,
                 bhh_n, nullptr, 1024, by * 256, bx * 128,
                 upd, nullptr, nullptr, nullptr, grz, gni, gated);
}

// out = float(upd) * sigmoid(upd @ Wog^T + bog)
__global__ __launch_bounds__(256, 2) void og_k(
    const bf16* __restrict__ upd, const bf16* __restrict__ wog,
    const float* __restrict__ og_b, float* __restrict__ out)
{
    __shared__ bf16 lds[36864];
    const int by = blockIdx.x & 31, bx = blockIdx.x >> 5;
    g256_core<2>(lds, upd, 1024, wog, 1024, 32,
                 nullptr, 0, nullptr, 0, 0,
                 og_b, nullptr, 1024, by * 256, bx * 128,
                 nullptr, out, nullptr, upd, nullptr, nullptr, nullptr);
}

// ---------------------------------------------------------------------------
// Triple-buffered GEMM core (small weight-composition GEMMs): BM x 128 tile.
// epi 0: out_bf = bf16(val);  epi 3: out_bf[gcol*tld + grow] (transposed)
// ---------------------------------------------------------------------------
template <int BM>
__device__ __forceinline__ void gemm_core_tb(
    bf16* sA, bf16* sB,
    const bf16* __restrict__ A, int lda,
    const bf16* __restrict__ W, int ldw,
    const float* __restrict__ bias,
    int N, int K, int brow, int bcol, int epi,
    bf16* __restrict__ out_bf, int tld)
{
    constexpr int AI = BM / 32;
    const int tid  = threadIdx.x;
    const int lane = tid & 63;
    const int wave = tid >> 6;
    const int wr   = (wave & 1) * (BM / 2);
    const int wc   = (wave >> 1) * 64;
    const int lrow = lane & 15;
    const int lq   = lane >> 4;

    f32x4 acc[AI][4];
#pragma unroll
    for (int i = 0; i < AI; ++i)
#pragma unroll
        for (int j = 0; j < 4; ++j) {
            f32x4 z = {0.0f, 0.0f, 0.0f, 0.0f};
            acc[i][j] = z;
        }

    auto stage = [&](bf16* dA, bf16* dB, int k0) {
#pragma unroll
        for (int i = 0; i < BM / 64; ++i) {
            const int s   = tid + i * 256;
            const int row = s >> 2;
            const int col = (((s & 3) ^ ((s >> 3) & 3)) << 3);
            const bf16* gp = A + (size_t)(brow + row) * lda + (k0 + col);
            __builtin_amdgcn_global_load_lds(
                (const __attribute__((address_space(1))) void*)gp,
                (__attribute__((address_space(3))) void*)(&dA[s * 8]),
                16, 0, 0);
        }
#pragma unroll
        for (int i = 0; i < 2; ++i) {
            const int s   = tid + i * 256;
            const int row = s >> 2;
            const int col = (((s & 3) ^ ((s >> 3) & 3)) << 3);
            const bf16* gp = W + (size_t)(bcol + row) * ldw + (k0 + col);
            __builtin_amdgcn_global_load_lds(
                (const __attribute__((address_space(1))) void*)gp,
                (__attribute__((address_space(3))) void*)(&dB[s * 8]),
                16, 0, 0);
        }
    };

#define WAIT_LPS()                                                   \
    do {                                                             \
        if constexpr (BM == 128)                                     \
            asm volatile("s_waitcnt vmcnt(4)" ::: "memory");         \
        else                                                         \
            asm volatile("s_waitcnt vmcnt(3)" ::: "memory");         \
    } while (0)

    const int NT = K >> 5;

    bf16* a0 = sA;               bf16* b0 = sB;
    bf16* a1 = sA + BM * 32;     bf16* b1 = sB + 4096;
    bf16* a2 = sA + 2 * BM * 32; bf16* b2 = sB + 2 * 4096;

    stage(a0, b0, 0);
    stage(a1, b1, NT > 1 ? 32 : 0);
    WAIT_LPS();
    __builtin_amdgcn_s_barrier();
    __builtin_amdgcn_sched_barrier(0);

    for (int kt = 0; kt < NT; ++kt) {
        bf16x8 av[AI], bv[4];
#pragma unroll
        for (int i = 0; i < AI; ++i) {
            const int r = wr + i * 16 + lrow;
            av[i] = *(const bf16x8*)&a0[r * 32 + ((lq ^ ((r >> 1) & 3)) << 3)];
        }
#pragma unroll
        for (int j = 0; j < 4; ++j) {
            const int r = wc + j * 16 + lrow;
            bv[j] = *(const bf16x8*)&b0[r * 32 + ((lq ^ ((r >> 1) & 3)) << 3)];
        }

        const int kn = (kt + 2 < NT ? kt + 2 : NT - 1) << 5;
        stage(a2, b2, kn);

#pragma unroll
        for (int i = 0; i < AI; ++i)
#pragma unroll
            for (int j = 0; j < 4; ++j)
                acc[i][j] = __builtin_amdgcn_mfma_f32_16x16x32_bf16(
                    av[i], bv[j], acc[i][j], 0, 0, 0);

        __builtin_amdgcn_sched_barrier(0);
        WAIT_LPS();
        __builtin_amdgcn_s_barrier();
        __builtin_amdgcn_sched_barrier(0);

        bf16* ta = a0; a0 = a1; a1 = a2; a2 = ta;
        bf16* tb = b0; b0 = b1; b1 = b2; b2 = tb;
    }

    asm volatile("s_waitcnt vmcnt(0)" ::: "memory");
#undef WAIT_LPS

    // epilogue: C/D layout col = lane&15, row = (lane>>4)*4 + reg
#pragma unroll
    for (int j = 0; j < 4; ++j) {
        const int gcol = bcol + wc + j * 16 + lrow;
        const float bj = bias ? bias[gcol] : 0.0f;
#pragma unroll
        for (int i = 0; i < AI; ++i) {
            const int growb = brow + wr + i * 16 + lq * 4;
#pragma unroll
            for (int r = 0; r < 4; ++r) {
                const int grow = growb + r;
                const float val = acc[i][j][r] + bj;
                if (epi == 0) {
                    out_bf[(size_t)grow * N + gcol] = (bf16)val;
                } else {
                    out_bf[(size_t)gcol * tld + grow] = (bf16)val;
                }
            }
        }
    }
}

__global__ __launch_bounds__(256, 2) void gemm64_k(
    const bf16* __restrict__ A, int lda, const bf16* __restrict__ W, int ldw,
    const float* __restrict__ bias, int N, int K, int epi,
    bf16* __restrict__ out_bf, int tld, int nby)
{
    __shared__ bf16 sA[3 * 64 * 32];
    __shared__ bf16 sB[3 * 128 * 32];
    const int by = blockIdx.x % nby;
    const int bx = blockIdx.x / nby;
    gemm_core_tb<64>(sA, sB, A, lda, W, ldw, bias, N, K,
                     by * 64, bx * 128, epi, out_bf, tld);
}

// ---------------------------------------------------------------------------
// Segmented prep kernel (one launch): cat-build | 6 weight casts | Wip^T |
// attention-ones. Segment boundaries in blocks (256 thr, 4 elems/thr):
//   [0,16384)        cat = [prev|input] -> bf16      (8192x2048)
//   [16384,27648)    casts: wv,wop,wih,wfg,wog,whh   (11.25M elems)
//   [27648,28672)    Wip^T transpose-cast            (1024x1024)
//   [28672,28680)    ones (attention weights)        (8192 f32)
// ---------------------------------------------------------------------------
__global__ void prep_k(
    const float* __restrict__ prev, const float* __restrict__ input,
    bf16* __restrict__ cat,
    const float* __restrict__ wv, const float* __restrict__ wop,
    const float* __restrict__ wih, const float* __restrict__ wfg,
    const float* __restrict__ wog, const float* __restrict__ whh,
    bf16* __restrict__ dv, bf16* __restrict__ dop, bf16* __restrict__ dih,
    bf16* __restrict__ dfg, bf16* __restrict__ dog, bf16* __restrict__ dhh,
    const float* __restrict__ ipw, bf16* __restrict__ wipt,
    float* __restrict__ ones)
{
    __shared__ float t[32][33];
    const int b = blockIdx.x;
    if (b < 16384) {
        const int i = b * 256 + threadIdx.x;
        const int row = i >> 9;
        const int c4  = i & 511;
        f32x4 v;
        if (c4 < 256)
            v = ((const f32x4*)prev)[(size_t)row * 256 + c4];
        else
            v = ((const f32x4*)input)[(size_t)row * 256 + (c4 - 256)];
        bf16x4 o = {(bf16)v[0], (bf16)v[1], (bf16)v[2], (bf16)v[3]};
        ((bf16x4*)cat)[i] = o;
    } else if (b < 27648) {
        const int c = (b - 16384) * 256 + threadIdx.x;
        const float* s; bf16* d; int o;
        if (c < 262144)        { s = wv;  d = dv;  o = c; }
        else if (c < 524288)   { s = wop; d = dop; o = c - 262144; }
        else if (c < 1310720)  { s = wih; d = dih; o = c - 524288; }
        else if (c < 1835008)  { s = wfg; d = dfg; o = c - 1310720; }
        else if (c < 2097152)  { s = wog; d = dog; o = c - 1835008; }
        else                   { s = whh; d = dhh; o = c - 2097152; }
        f32x4 v = ((const f32x4*)s)[o];
        bf16x4 w = {(bf16)v[0], (bf16)v[1], (bf16)v[2], (bf16)v[3]};
        ((bf16x4*)d)[o] = w;
    } else if (b < 28672) {
        const int b2 = b - 27648;
        const int bx = (b2 & 31) * 32;
        const int by = (b2 >> 5) * 32;
        const int tx = threadIdx.x & 31, ty = threadIdx.x >> 5;
#pragma unroll
        for (int i = 0; i < 32; i += 8)
            t[ty + i][tx] = ipw[(size_t)(by + ty + i) * 1024 + bx + tx];
        __syncthreads();
#pragma unroll
        for (int i = 0; i < 32; i += 8)
            wipt[(size_t)(bx + ty + i) * 1024 + by + tx] = (bf16)t[tx][ty + i];
    } else {
        const int i = (b - 28672) * 256 + threadIdx.x;
        if (i < 2048) {
            f32x4 one = {1.0f, 1.0f, 1.0f, 1.0f};
            ((f32x4*)ones)[i] = one;
        }
    }
}

// y[n] = b[n] + sum_k W[n,k] * x[k]   (fp32; one wave per output row)
__global__ void gemv_k(const float* __restrict__ W, const float* __restrict__ x,
                       const float* __restrict__ b, float* __restrict__ y,
                       int K) {
    int n    = blockIdx.x * 4 + (threadIdx.x >> 6);
    int lane = threadIdx.x & 63;
    const float* row = W + (size_t)n * K;
    float s = 0.0f;
    for (int k = lane * 4; k < K; k += 256) {
        f32x4 w = *(const f32x4*)(row + k);
        f32x4 xv = *(const f32x4*)(x + k);
        s += w[0] * xv[0] + w[1] * xv[1] + w[2] * xv[2] + w[3] * xv[3];
    }
#pragma unroll
    for (int off = 32; off; off >>= 1) s += __shfl_down(s, off);
    if (lane == 0) y[n] = s + b[n];
}

// ---------------------------------------------------------------------------
// Launch
// ---------------------------------------------------------------------------
extern "C" void kernel_launch(void* const* d_in, const int* in_sizes, int n_in,
                              void* d_out, int out_size, void* d_ws,
                              size_t ws_size, hipStream_t stream) {
    const float* input      = (const float*)d_in[0];
    const float* prev       = (const float*)d_in[1];
    const float* in_proj_w  = (const float*)d_in[2];
    const float* in_proj_b  = (const float*)d_in[3];
    const float* out_proj_w = (const float*)d_in[4];
    const float* out_proj_b = (const float*)d_in[5];
    const float* ip_w       = (const float*)d_in[6];
    const float* ip_b       = (const float*)d_in[7];
    // d_in[8]/d_in[9] (mp_w/mp_b) dead: softmax over one key == 1
    const float* fg_w  = (const float*)d_in[10];
    const float* fg_b  = (const float*)d_in[11];
    const float* og_w  = (const float*)d_in[12];
    const float* og_b  = (const float*)d_in[13];
    const float* gih_w = (const float*)d_in[14];
    const float* gih_b = (const float*)d_in[15];
    const float* ghh_w = (const float*)d_in[16];
    const float* ghh_b = (const float*)d_in[17];
    float* out = (float*)d_out;

    // ---- workspace layout (no overlap tricks; fits 152 MiB proven bound)
    char* ws = (char*)d_ws;
    const size_t MB = 1024 * 1024;
    bf16* CAT   = (bf16*)(ws);              // [0,32M)   [prev|input] bf16
    bf16* WHHB  = (bf16*)(ws + 32 * MB);    // [32,38M)  Whh bf16 (3072x1024)
    bf16* GRZ   = (bf16*)(ws + 38 * MB);    // [38,70M)  r,z sums (8192x2048)
    bf16* GNI   = (bf16*)(ws + 70 * MB);    // [70,86M)  gi_n (8192x1024)
    bf16* GATED = (bf16*)(ws + 86 * MB);    // [86,102M) gated mem
    bf16* UPD   = (bf16*)(ws + 102 * MB);   // [102,118M) updated mem
    bf16* WCOMB = (bf16*)(ws + 118 * MB);   // [118,124M) (3072x1024)
    bf16* WOGB  = (bf16*)(ws + 124 * MB);   // [124,126M)
    bf16* WFGB  = (bf16*)(ws + 126 * MB);   // [126,130M) (1024x2048)
    bf16* WVB   = (bf16*)(ws + 130 * MB);   // [130,132M)
    bf16* WOPB  = (bf16*)(ws + 132 * MB);   // [132,134M)
    bf16* WIHB  = (bf16*)(ws + 134 * MB);   // [134,140M) (3072x1024)
    bf16* WIPT  = (bf16*)(ws + 140 * MB);   // [140,142M)
    bf16* T1T   = (bf16*)(ws + 142 * MB);   // [142,144M)
    bf16* T2T   = (bf16*)(ws + 144 * MB);   // [144,146M)
    float* T1B  = (float*)(ws + 146 * MB);
    float* T2B  = (float*)(ws + 146 * MB + 8192);
    float* T3B  = (float*)(ws + 146 * MB + 16384);  // 3072 f32

    const int M = B_ROWS;
    dim3 blk(256);

    // 1. all elementwise prep in ONE launch (cat, 6 casts, Wip^T, ones)
    prep_k<<<dim3(28680), blk, 0, stream>>>(
        prev, input, CAT,
        in_proj_w + 2048 * 1024, out_proj_w, gih_w, fg_w, og_w, ghh_w,
        WVB, WOPB, WIHB, WFGB, WOGB, WHHB,
        ip_w, WIPT, out + (size_t)M * 1024);
    // 2. bias chain (fp32, exact): T3 = Wih@(Wop@(Wv@ip_b + bv) + bop) + bih
    gemv_k<<<dim3(256), blk, 0, stream>>>(in_proj_w + 2048 * 1024, ip_b, in_proj_b + 2048, T1B, 1024);
    gemv_k<<<dim3(256), blk, 0, stream>>>(out_proj_w, T1B, out_proj_b, T2B, 1024);
    gemv_k<<<dim3(768), blk, 0, stream>>>(gih_w, T2B, gih_b, T3B, 1024);
    // 3-5. weight composition: Wcomb = Wih @ Wop @ Wv @ Wip
    gemm64_k<<<dim3(128), blk, 0, stream>>>(WVB, 1024, WIPT, 1024, nullptr,
        1024, 1024, 3, T1T, 1024, 16);  // (Wv@Wip)^T
    gemm64_k<<<dim3(128), blk, 0, stream>>>(WOPB, 1024, T1T, 1024, nullptr,
        1024, 1024, 3, T2T, 1024, 16);  // (Wop@..)^T
    gemm64_k<<<dim3(384), blk, 0, stream>>>(WIHB, 1024, T2T, 1024, nullptr,
        1024, 1024, 0, WCOMB, 0, 48);   // Wcomb [3072,1024]
    // 6. fg (gated = prev*sig(cat@Wfg^T+b)) + gi_n (x@Wcomb_n^T+b) merged
    fgg1_k<<<dim3(512), blk, 0, stream>>>(
        CAT, WFGB, fg_b, prev, GATED,
        WCOMB + (size_t)2048 * 1024, T3B + 2048, GNI);
    // 7. Grz = x@Wcomb_rz^T + gated@Whh_rz^T + (T3B+bhh)  [two-phase K]
    g2_k<<<dim3(512), blk, 0, stream>>>(
        CAT + 1024, WCOMB, GATED, WHHB, T3B, ghh_b, GRZ);
    // 8. gh_n GEMM + fused GRU combine -> UPD
    g3_k<<<dim3(256), blk, 0, stream>>>(
        GATED, WHHB + (size_t)2048 * 1024, ghh_b + 2048, GRZ, GNI, UPD);
    // 9. out = upd * sigmoid(upd @ Wog^T + bog)
    og_k<<<dim3(256), blk, 0, stream>>>(UPD, WOGB, og_b, out);
}

// Round 9
// 434.579 us; speedup vs baseline: 1.2236x; 1.0475x over previous
//
#include <hip/hip_runtime.h>
#include <cstdint>
#include <cstddef>

// ---------------------------------------------------------------------------
// DynamicMemoryCell on MI355X (gfx950) — round 12 (resubmit; round-8 bench
// failed with "container failed twice" — infra error, kernel never executed)
//
// Math: softmax over 1 key == 1 -> attn == v; q/k/pm dead.
// Linear chain pi->v->ctx->gi collapsed: Wcomb = Wih@Wop@Wv@Wip (per call).
// GRU algebra: r,z need only SUMS gi+gh -> one two-phase-K GEMM (g2);
// combine fused into gh_n GEMM epilogue (g3).
//
// Round-12 vs round-11 (455us): kernel-sum ~280 vs 455 measured -> ~170us of
// inter-launch gap over 10 launches is the top residual. This round packs
// independent work into shared launches (block-id branches, the validated
// fgg1 pattern). 10 -> 7 launches:
//   L1 prep_k   : cat + 6 casts + Wip^T + ones + gemv1(T1B)
//   L2 comb1_k  : gemm64(T1T) + gemv2(T2B) + FG (fg needs only L1 outputs
//                 -> moved 3 launches earlier, overlaps the small work)
//   L3 comb2_k  : gemm64(T2T) + gemv3(T3B)
//   L4 gemm64_k : Wcomb
//   L5 big_k    : g2 (Grz, two-phase K) + gi_n   (768 blocks = 3/CU TLP)
//   L6 g3_k     : gh_n GEMM + fused GRU combine -> UPD
//   L7 og_k     : out = upd * sig(upd@Wog^T+bog)
// GEMM cores unchanged from round-11 (verified): 256x128 triple-buffered
// counted-vmcnt(6) g256_core; gemm_core_tb<64> for weight composition.
// ---------------------------------------------------------------------------

typedef __bf16 bf16;
typedef bf16 bf16x4 __attribute__((ext_vector_type(4)));
typedef bf16 bf16x8 __attribute__((ext_vector_type(8)));
typedef float f32x4 __attribute__((ext_vector_type(4)));

#define B_ROWS 8192

__device__ __forceinline__ float sigmoid_f(float x) {
    return 1.0f / (1.0f + __expf(-x));
}
__device__ __forceinline__ float tanh_f(float x) {
    return 1.0f - 2.0f / (__expf(2.0f * x) + 1.0f);
}

// ---------------------------------------------------------------------------
// 256x128 triple-buffered GEMM core (verified round-10/11). 4 waves (2Mx2N),
// wave tile 128x64, acc[8][4]. LDS 72 KiB (3-buf A/B); reused as C-stage.
// Counted vmcnt(6): one 6-load stage stays in flight across each barrier.
// Two K-phases: tiles [0,nt1) from A1/W1, [nt1,nt1+nt2) from A2/W2.
// EPI 0: out_bf = bf16(acc + bias1 [+ bias2])
// EPI 1: out_bf = bf16(aux_f32 * sigmoid(val))            (forget gate)
// EPI 2: out_f32 = float(aux_bf) * sigmoid(val)           (output gate)
// EPI 4: GRU combine: val = gh_n; r,z from GRZ, gi_n from GNI, mem from GAT
// ---------------------------------------------------------------------------
template <int EPI>
__device__ __forceinline__ void g256_core(
    bf16* lds,
    const bf16* A1, int lda1, const bf16* W1, int ldw1, int nt1,
    const bf16* A2, int lda2, const bf16* W2, int ldw2, int nt2,
    const float* bias1, const float* bias2,
    int N, int brow, int bcol,
    bf16* out_bf, float* out_f32,
    const float* aux_f32, const bf16* aux_bf,
    const bf16* grz, const bf16* gni, const bf16* gat)
{
    bf16* sA = lds;                       // 3 x 256 x 32
    bf16* sB = lds + 3 * 256 * 32;        // 3 x 128 x 32

    const int tid  = threadIdx.x;
    const int lane = tid & 63;
    const int wave = tid >> 6;
    const int wm   = wave >> 1;          // M half (128 rows)
    const int wn   = wave & 1;           // N half (64 cols)
    const int lrow = lane & 15;
    const int lq   = lane >> 4;

    f32x4 acc[8][4];
#pragma unroll
    for (int i = 0; i < 8; ++i)
#pragma unroll
        for (int j = 0; j < 4; ++j) {
            f32x4 z = {0.0f, 0.0f, 0.0f, 0.0f};
            acc[i][j] = z;
        }

    // stage K-tile kt: A 4 insts (256 rows), B 2 insts (128 rows). LDS dest
    // linear (rule #21); swizzle via permuted GLOBAL source col.
    auto stage = [&](bf16* dA, bf16* dB, int kt) {
        const bf16* Ab; int lda; const bf16* Wb; int ldw; int k0;
        if (kt < nt1) { Ab = A1; lda = lda1; Wb = W1; ldw = ldw1; k0 = kt << 5; }
        else          { Ab = A2; lda = lda2; Wb = W2; ldw = ldw2; k0 = (kt - nt1) << 5; }
#pragma unroll
        for (int i = 0; i < 4; ++i) {
            const int s   = tid + i * 256;
            const int row = s >> 2;
            const int col = (((s & 3) ^ ((s >> 3) & 3)) << 3);
            const bf16* gp = Ab + (size_t)(brow + row) * lda + (k0 + col);
            __builtin_amdgcn_global_load_lds(
                (const __attribute__((address_space(1))) void*)gp,
                (__attribute__((address_space(3))) void*)(&dA[s * 8]),
                16, 0, 0);
        }
#pragma unroll
        for (int i = 0; i < 2; ++i) {
            const int s   = tid + i * 256;
            const int row = s >> 2;
            const int col = (((s & 3) ^ ((s >> 3) & 3)) << 3);
            const bf16* gp = Wb + (size_t)(bcol + row) * ldw + (k0 + col);
            __builtin_amdgcn_global_load_lds(
                (const __attribute__((address_space(1))) void*)gp,
                (__attribute__((address_space(3))) void*)(&dB[s * 8]),
                16, 0, 0);
        }
    };

    const int NT = nt1 + nt2;

    bf16* a0 = sA;           bf16* b0 = sB;
    bf16* a1 = sA + 8192;    bf16* b1 = sB + 4096;
    bf16* a2 = sA + 16384;   bf16* b2 = sB + 8192;

    stage(a0, b0, 0);
    stage(a1, b1, 1);
    asm volatile("s_waitcnt vmcnt(6)" ::: "memory");  // tile 0 landed
    __builtin_amdgcn_s_barrier();
    __builtin_amdgcn_sched_barrier(0);

    for (int kt = 0; kt < NT; ++kt) {
        bf16x8 av[8], bv[4];
#pragma unroll
        for (int i = 0; i < 8; ++i) {
            const int r = wm * 128 + i * 16 + lrow;
            av[i] = *(const bf16x8*)&a0[r * 32 + ((lq ^ ((r >> 1) & 3)) << 3)];
        }
#pragma unroll
        for (int j = 0; j < 4; ++j) {
            const int r = wn * 64 + j * 16 + lrow;
            bv[j] = *(const bf16x8*)&b0[r * 32 + ((lq ^ ((r >> 1) & 3)) << 3)];
        }

        // tile kt+2 into the free buffer (tail re-stages: uniform FIFO)
        stage(a2, b2, kt + 2 < NT ? kt + 2 : NT - 1);

#pragma unroll
        for (int i = 0; i < 8; ++i)
#pragma unroll
            for (int j = 0; j < 4; ++j)
                acc[i][j] = __builtin_amdgcn_mfma_f32_16x16x32_bf16(
                    av[i], bv[j], acc[i][j], 0, 0, 0);

        __builtin_amdgcn_sched_barrier(0);
        asm volatile("s_waitcnt vmcnt(6)" ::: "memory"); // kt+1 landed
        __builtin_amdgcn_s_barrier();
        __builtin_amdgcn_sched_barrier(0);

        bf16* ta = a0; a0 = a1; a1 = a2; a2 = ta;
        bf16* tb = b0; b0 = b1; b1 = b2; b2 = tb;
    }

    // drain redundant tail stages; BLOCK barrier before LDS reuse (per-wave
    // vmcnt doesn't order other waves' in-flight global_load_lds writes)
    asm volatile("s_waitcnt vmcnt(0)" ::: "memory");
    __syncthreads();

    if constexpr (EPI == 0) {
        // ---- bf16 C-stage (stride 136: 2-way-max), coalesced b128 flush --
        bf16* cb = lds;
#pragma unroll
        for (int j = 0; j < 4; ++j) {
            const int col = wn * 64 + j * 16 + lrow;
            float bj = bias1[bcol + col];
            if (bias2) bj += bias2[bcol + col];
#pragma unroll
            for (int i = 0; i < 8; ++i) {
                const int rowb = wm * 128 + i * 16 + lq * 4;
#pragma unroll
                for (int r = 0; r < 4; ++r)
                    cb[(rowb + r) * 136 + col] = (bf16)(acc[i][j][r] + bj);
            }
        }
        __syncthreads();
#pragma unroll
        for (int p = 0; p < 16; ++p) {
            const int row = p * 16 + (tid >> 4);
            const int col = (tid & 15) * 8;
            bf16x8 v = *(const bf16x8*)&cb[row * 136 + col];
            *(bf16x8*)&out_bf[(size_t)(brow + row) * N + bcol + col] = v;
        }
    } else {
        // ---- f32 C-stage in two 128-row halves (exact activation input) --
        float* cf = (float*)lds;           // 128 x 132 f32 = 67.5 KiB
#pragma unroll
        for (int h = 0; h < 2; ++h) {
            if (wm == h) {
#pragma unroll
                for (int j = 0; j < 4; ++j) {
                    const int col = wn * 64 + j * 16 + lrow;
                    const float bj = bias1[bcol + col];
#pragma unroll
                    for (int i = 0; i < 8; ++i) {
                        const int rl = i * 16 + lq * 4;
#pragma unroll
                        for (int r = 0; r < 4; ++r)
                            cf[(rl + r) * 132 + col] = acc[i][j][r] + bj;
                    }
                }
            }
            __syncthreads();
#pragma unroll
            for (int p = 0; p < 16; ++p) {
                const int idx = p * 256 + tid;
                const int row = idx >> 5;
                const int ch  = idx & 31;
                f32x4 v = *(const f32x4*)&cf[row * 132 + ch * 4];
                const int grow = brow + h * 128 + row;
                const int gcol = bcol + ch * 4;
                const size_t gidx = (size_t)grow * N + gcol;
                if constexpr (EPI == 1) {
                    f32x4 a4 = *(const f32x4*)&aux_f32[gidx];
                    bf16x4 o;
#pragma unroll
                    for (int e = 0; e < 4; ++e)
                        o[e] = (bf16)(a4[e] * sigmoid_f(v[e]));
                    *(bf16x4*)&out_bf[gidx] = o;
                } else if constexpr (EPI == 2) {
                    bf16x4 ab = *(const bf16x4*)&aux_bf[gidx];
                    f32x4 o;
#pragma unroll
                    for (int e = 0; e < 4; ++e)
                        o[e] = (float)ab[e] * sigmoid_f(v[e]);
                    *(f32x4*)&out_f32[gidx] = o;
                } else {
                    // EPI == 4: GRU combine. v = gh_n (f32). N == 1024.
                    const bf16* pr = grz + (size_t)grow * 2048 + gcol;
                    bf16x4 rr = *(const bf16x4*)pr;          // r sums
                    bf16x4 zz = *(const bf16x4*)(pr + 1024); // z sums
                    bf16x4 g4 = *(const bf16x4*)&gni[gidx];  // gi_n
                    bf16x4 m4 = *(const bf16x4*)&gat[gidx];  // gated mem
                    bf16x4 o;
#pragma unroll
                    for (int e = 0; e < 4; ++e) {
                        const float r = sigmoid_f((float)rr[e]);
                        const float z = sigmoid_f((float)zz[e]);
                        const float n = tanh_f((float)g4[e] + r * v[e]);
                        o[e] = (bf16)((1.0f - z) * n + z * (float)m4[e]);
                    }
                    *(bf16x4*)&out_bf[gidx] = o;
                }
            }
            __syncthreads();
        }
    }
}

// ---------------------------------------------------------------------------
// Triple-buffered BM x 128 core (weight composition, verified).
// epi 0: out_bf = bf16(val);  epi 3: out_bf[gcol*tld + grow] (transposed)
// ---------------------------------------------------------------------------
template <int BM>
__device__ __forceinline__ void gemm_core_tb(
    bf16* sA, bf16* sB,
    const bf16* __restrict__ A, int lda,
    const bf16* __restrict__ W, int ldw,
    const float* __restrict__ bias,
    int N, int K, int brow, int bcol, int epi,
    bf16* __restrict__ out_bf, int tld)
{
    constexpr int AI = BM / 32;
    const int tid  = threadIdx.x;
    const int lane = tid & 63;
    const int wave = tid >> 6;
    const int wr   = (wave & 1) * (BM / 2);
    const int wc   = (wave >> 1) * 64;
    const int lrow = lane & 15;
    const int lq   = lane >> 4;

    f32x4 acc[AI][4];
#pragma unroll
    for (int i = 0; i < AI; ++i)
#pragma unroll
        for (int j = 0; j < 4; ++j) {
            f32x4 z = {0.0f, 0.0f, 0.0f, 0.0f};
            acc[i][j] = z;
        }

    auto stage = [&](bf16* dA, bf16* dB, int k0) {
#pragma unroll
        for (int i = 0; i < BM / 64; ++i) {
            const int s   = tid + i * 256;
            const int row = s >> 2;
            const int col = (((s & 3) ^ ((s >> 3) & 3)) << 3);
            const bf16* gp = A + (size_t)(brow + row) * lda + (k0 + col);
            __builtin_amdgcn_global_load_lds(
                (const __attribute__((address_space(1))) void*)gp,
                (__attribute__((address_space(3))) void*)(&dA[s * 8]),
                16, 0, 0);
        }
#pragma unroll
        for (int i = 0; i < 2; ++i) {
            const int s   = tid + i * 256;
            const int row = s >> 2;
            const int col = (((s & 3) ^ ((s >> 3) & 3)) << 3);
            const bf16* gp = W + (size_t)(bcol + row) * ldw + (k0 + col);
            __builtin_amdgcn_global_load_lds(
                (const __attribute__((address_space(1))) void*)gp,
                (__attribute__((address_space(3))) void*)(&dB[s * 8]),
                16, 0, 0);
        }
    };

#define WAIT_LPS()                                                   \
    do {                                                             \
        if constexpr (BM == 128)                                     \
            asm volatile("s_waitcnt vmcnt(4)" ::: "memory");         \
        else                                                         \
            asm volatile("s_waitcnt vmcnt(3)" ::: "memory");         \
    } while (0)

    const int NT = K >> 5;

    bf16* a0 = sA;               bf16* b0 = sB;
    bf16* a1 = sA + BM * 32;     bf16* b1 = sB + 4096;
    bf16* a2 = sA + 2 * BM * 32; bf16* b2 = sB + 2 * 4096;

    stage(a0, b0, 0);
    stage(a1, b1, NT > 1 ? 32 : 0);
    WAIT_LPS();
    __builtin_amdgcn_s_barrier();
    __builtin_amdgcn_sched_barrier(0);

    for (int kt = 0; kt < NT; ++kt) {
        bf16x8 av[AI], bv[4];
#pragma unroll
        for (int i = 0; i < AI; ++i) {
            const int r = wr + i * 16 + lrow;
            av[i] = *(const bf16x8*)&a0[r * 32 + ((lq ^ ((r >> 1) & 3)) << 3)];
        }
#pragma unroll
        for (int j = 0; j < 4; ++j) {
            const int r = wc + j * 16 + lrow;
            bv[j] = *(const bf16x8*)&b0[r * 32 + ((lq ^ ((r >> 1) & 3)) << 3)];
        }

        const int kn = (kt + 2 < NT ? kt + 2 : NT - 1) << 5;
        stage(a2, b2, kn);

#pragma unroll
        for (int i = 0; i < AI; ++i)
#pragma unroll
            for (int j = 0; j < 4; ++j)
                acc[i][j] = __builtin_amdgcn_mfma_f32_16x16x32_bf16(
                    av[i], bv[j], acc[i][j], 0, 0, 0);

        __builtin_amdgcn_sched_barrier(0);
        WAIT_LPS();
        __builtin_amdgcn_s_barrier();
        __builtin_amdgcn_sched_barrier(0);

        bf16* ta = a0; a0 = a1; a1 = a2; a2 = ta;
        bf16* tb = b0; b0 = b1; b1 = b2; b2 = tb;
    }

    asm volatile("s_waitcnt vmcnt(0)" ::: "memory");
#undef WAIT_LPS

#pragma unroll
    for (int j = 0; j < 4; ++j) {
        const int gcol = bcol + wc + j * 16 + lrow;
        const float bj = bias ? bias[gcol] : 0.0f;
#pragma unroll
        for (int i = 0; i < AI; ++i) {
            const int growb = brow + wr + i * 16 + lq * 4;
#pragma unroll
            for (int r = 0; r < 4; ++r) {
                const int grow = growb + r;
                const float val = acc[i][j][r] + bj;
                if (epi == 0) {
                    out_bf[(size_t)grow * N + gcol] = (bf16)val;
                } else {
                    out_bf[(size_t)gcol * tld + grow] = (bf16)val;
                }
            }
        }
    }
}

// fp32 gemv rows: y[n] = b[n] + W[n,:]@x, one wave per row, K=1024
__device__ __forceinline__ void gemv_rows(
    const float* __restrict__ W, const float* __restrict__ x,
    const float* __restrict__ b, float* __restrict__ y, int nbase)
{
    const int n    = nbase + (threadIdx.x >> 6);
    const int lane = threadIdx.x & 63;
    const float* row = W + (size_t)n * 1024;
    float s = 0.0f;
    for (int k = lane * 4; k < 1024; k += 256) {
        f32x4 w = *(const f32x4*)(row + k);
        f32x4 xv = *(const f32x4*)(x + k);
        s += w[0] * xv[0] + w[1] * xv[1] + w[2] * xv[2] + w[3] * xv[3];
    }
#pragma unroll
    for (int off = 32; off; off >>= 1) s += __shfl_down(s, off);
    if (lane == 0) y[n] = s + b[n];
}

// ---------------------------------------------------------------------------
// L1: segmented prep (one launch): cat | 6 casts | Wip^T | ones | gemv1.
//   [0,16384)        cat = [prev|input] -> bf16      (8192x2048)
//   [16384,27648)    casts: wv,wop,wih,wfg,wog,whh
//   [27648,28672)    Wip^T transpose-cast
//   [28672,28680)    ones (attention weights)
//   [28680,28936)    gemv1: T1B = Wv@ip_b + bv       (f32)
// ---------------------------------------------------------------------------
__global__ void prep_k(
    const float* __restrict__ prev, const float* __restrict__ input,
    bf16* __restrict__ cat,
    const float* __restrict__ wv, const float* __restrict__ wop,
    const float* __restrict__ wih, const float* __restrict__ wfg,
    const float* __restrict__ wog, const float* __restrict__ whh,
    bf16* __restrict__ dv, bf16* __restrict__ dop, bf16* __restrict__ dih,
    bf16* __restrict__ dfg, bf16* __restrict__ dog, bf16* __restrict__ dhh,
    const float* __restrict__ ipw, bf16* __restrict__ wipt,
    float* __restrict__ ones,
    const float* __restrict__ ip_b, const float* __restrict__ bv,
    float* __restrict__ t1b)
{
    __shared__ float t[32][33];
    const int b = blockIdx.x;
    if (b < 16384) {
        const int i = b * 256 + threadIdx.x;
        const int row = i >> 9;
        const int c4  = i & 511;
        f32x4 v;
        if (c4 < 256)
            v = ((const f32x4*)prev)[(size_t)row * 256 + c4];
        else
            v = ((const f32x4*)input)[(size_t)row * 256 + (c4 - 256)];
        bf16x4 o = {(bf16)v[0], (bf16)v[1], (bf16)v[2], (bf16)v[3]};
        ((bf16x4*)cat)[i] = o;
    } else if (b < 27648) {
        const int c = (b - 16384) * 256 + threadIdx.x;
        const float* s; bf16* d; int o;
        if (c < 262144)        { s = wv;  d = dv;  o = c; }
        else if (c < 524288)   { s = wop; d = dop; o = c - 262144; }
        else if (c < 1310720)  { s = wih; d = dih; o = c - 524288; }
        else if (c < 1835008)  { s = wfg; d = dfg; o = c - 1310720; }
        else if (c < 2097152)  { s = wog; d = dog; o = c - 1835008; }
        else                   { s = whh; d = dhh; o = c - 2097152; }
        f32x4 v = ((const f32x4*)s)[o];
        bf16x4 w = {(bf16)v[0], (bf16)v[1], (bf16)v[2], (bf16)v[3]};
        ((bf16x4*)d)[o] = w;
    } else if (b < 28672) {
        const int b2 = b - 27648;
        const int bx = (b2 & 31) * 32;
        const int by = (b2 >> 5) * 32;
        const int tx = threadIdx.x & 31, ty = threadIdx.x >> 5;
#pragma unroll
        for (int i = 0; i < 32; i += 8)
            t[ty + i][tx] = ipw[(size_t)(by + ty + i) * 1024 + bx + tx];
        __syncthreads();
#pragma unroll
        for (int i = 0; i < 32; i += 8)
            wipt[(size_t)(bx + ty + i) * 1024 + by + tx] = (bf16)t[tx][ty + i];
    } else if (b < 28680) {
        const int i = (b - 28672) * 256 + threadIdx.x;
        if (i < 2048) {
            f32x4 one = {1.0f, 1.0f, 1.0f, 1.0f};
            ((f32x4*)ones)[i] = one;
        }
    } else {
        gemv_rows(wv, ip_b, bv, t1b, (b - 28680) * 4);
    }
}

// L2: gemm64(T1T, 128 blk) + gemv2(T2B, 256 blk) + fg (256 blk, epi1)
__global__ __launch_bounds__(256, 2) void comb1_k(
    const bf16* __restrict__ wvb, const bf16* __restrict__ wipt,
    bf16* __restrict__ t1t,
    const float* __restrict__ wop_f, const float* __restrict__ t1b,
    const float* __restrict__ bop, float* __restrict__ t2b,
    const bf16* __restrict__ cat, const bf16* __restrict__ wfgb,
    const float* __restrict__ fg_b, const float* __restrict__ prev,
    bf16* __restrict__ gated)
{
    __shared__ bf16 lds[36864];
    const int b = blockIdx.x;
    if (b < 128) {
        const int by = b % 16, bx = b / 16;
        gemm_core_tb<64>(lds, lds + 3 * 64 * 32, wvb, 1024, wipt, 1024,
                         nullptr, 1024, 1024, by * 64, bx * 128, 3, t1t, 1024);
    } else if (b < 384) {
        gemv_rows(wop_f, t1b, bop, t2b, (b - 128) * 4);
    } else {
        const int id = b - 384;
        const int by = id & 31, bx = id >> 5;
        g256_core<1>(lds, cat, 2048, wfgb, 2048, 64,
                     nullptr, 0, nullptr, 0, 0,
                     fg_b, nullptr, 1024, by * 256, bx * 128,
                     gated, nullptr, prev, nullptr, nullptr, nullptr, nullptr);
    }
}

// L3: gemm64(T2T, 128 blk) + gemv3(T3B, 768 blk)
__global__ __launch_bounds__(256, 2) void comb2_k(
    const bf16* __restrict__ wopb, const bf16* __restrict__ t1t,
    bf16* __restrict__ t2t,
    const float* __restrict__ wih_f, const float* __restrict__ t2b,
    const float* __restrict__ bih, float* __restrict__ t3b)
{
    __shared__ bf16 lds[36864];
    const int b = blockIdx.x;
    if (b < 128) {
        const int by = b % 16, bx = b / 16;
        gemm_core_tb<64>(lds, lds + 3 * 64 * 32, wopb, 1024, t1t, 1024,
                         nullptr, 1024, 1024, by * 64, bx * 128, 3, t2t, 1024);
    } else {
        gemv_rows(wih_f, t2b, bih, t3b, (b - 128) * 4);
    }
}

// L4: Wcomb = Wih @ T2T^T  (384 blocks, nby=48, epi0)
__global__ __launch_bounds__(256, 2) void gemm64_k(
    const bf16* __restrict__ A, const bf16* __restrict__ W,
    bf16* __restrict__ out_bf)
{
    __shared__ bf16 sA[3 * 64 * 32];
    __shared__ bf16 sB[3 * 128 * 32];
    const int by = blockIdx.x % 48;
    const int bx = blockIdx.x / 48;
    gemm_core_tb<64>(sA, sB, A, 1024, W, 1024, nullptr,
                     1024, 1024, by * 64, bx * 128, 0, out_bf, 0);
}

// L5: g2 (Grz two-phase, 512 blk) + gi_n (256 blk)
__global__ __launch_bounds__(256, 2) void big_k(
    const bf16* __restrict__ x, const bf16* __restrict__ wcomb,
    const bf16* __restrict__ gated, const bf16* __restrict__ whh,
    const float* __restrict__ t3b, const float* __restrict__ bhh,
    bf16* __restrict__ grz,
    const bf16* __restrict__ wcomb_n, const float* __restrict__ bias_n,
    bf16* __restrict__ gni)
{
    __shared__ bf16 lds[36864];
    const int b = blockIdx.x;
    if (b < 512) {
        const int by = b & 31, bx = b >> 5;   // bx 0..15
        g256_core<0>(lds, x, 2048, wcomb, 1024, 32,
                     gated, 1024, whh, 1024, 32,
                     t3b, bhh, 2048, by * 256, bx * 128,
                     grz, nullptr, nullptr, nullptr, nullptr, nullptr, nullptr);
    } else {
        const int id = b - 512;
        const int by = id & 31, bx = id >> 5; // bx 0..7
        g256_core<0>(lds, x, 2048, wcomb_n, 1024, 32,
                     nullptr, 0, nullptr, 0, 0,
                     bias_n, nullptr, 1024, by * 256, bx * 128,
                     gni, nullptr, nullptr, nullptr, nullptr, nullptr, nullptr);
    }
}

// L6: gh_n GEMM + fused GRU combine epilogue -> UPD
__global__ __launch_bounds__(256, 2) void g3_k(
    const bf16* __restrict__ gated, const bf16* __restrict__ whh_n,
    const float* __restrict__ bhh_n,
    const bf16* __restrict__ grz, const bf16* __restrict__ gni,
    bf16* __restrict__ upd)
{
    __shared__ bf16 lds[36864];
    const int by = blockIdx.x & 31, bx = blockIdx.x >> 5;
    g256_core<4>(lds, gated, 1024, whh_n, 1024, 32,
                 nullptr, 0, nullptr, 0, 0,
                 bhh_n, nullptr, 1024, by * 256, bx * 128,
                 upd, nullptr, nullptr, nullptr, grz, gni, gated);
}

// L7: out = float(upd) * sigmoid(upd @ Wog^T + bog)
__global__ __launch_bounds__(256, 2) void og_k(
    const bf16* __restrict__ upd, const bf16* __restrict__ wog,
    const float* __restrict__ og_b, float* __restrict__ out)
{
    __shared__ bf16 lds[36864];
    const int by = blockIdx.x & 31, bx = blockIdx.x >> 5;
    g256_core<2>(lds, upd, 1024, wog, 1024, 32,
                 nullptr, 0, nullptr, 0, 0,
                 og_b, nullptr, 1024, by * 256, bx * 128,
                 nullptr, out, nullptr, upd, nullptr, nullptr, nullptr);
}

// ---------------------------------------------------------------------------
// Launch
// ---------------------------------------------------------------------------
extern "C" void kernel_launch(void* const* d_in, const int* in_sizes, int n_in,
                              void* d_out, int out_size, void* d_ws,
                              size_t ws_size, hipStream_t stream) {
    const float* input      = (const float*)d_in[0];
    const float* prev       = (const float*)d_in[1];
    const float* in_proj_w  = (const float*)d_in[2];
    const float* in_proj_b  = (const float*)d_in[3];
    const float* out_proj_w = (const float*)d_in[4];
    const float* out_proj_b = (const float*)d_in[5];
    const float* ip_w       = (const float*)d_in[6];
    const float* ip_b       = (const float*)d_in[7];
    // d_in[8]/d_in[9] (mp_w/mp_b) dead: softmax over one key == 1
    const float* fg_w  = (const float*)d_in[10];
    const float* fg_b  = (const float*)d_in[11];
    const float* og_w  = (const float*)d_in[12];
    const float* og_b  = (const float*)d_in[13];
    const float* gih_w = (const float*)d_in[14];
    const float* gih_b = (const float*)d_in[15];
    const float* ghh_w = (const float*)d_in[16];
    const float* ghh_b = (const float*)d_in[17];
    float* out = (float*)d_out;

    // ---- workspace layout
    char* ws = (char*)d_ws;
    const size_t MB = 1024 * 1024;
    bf16* CAT   = (bf16*)(ws);              // [0,32M)   [prev|input] bf16
    bf16* WHHB  = (bf16*)(ws + 32 * MB);    // [32,38M)  Whh bf16 (3072x1024)
    bf16* GRZ   = (bf16*)(ws + 38 * MB);    // [38,70M)  r,z sums (8192x2048)
    bf16* GNI   = (bf16*)(ws + 70 * MB);    // [70,86M)  gi_n (8192x1024)
    bf16* GATED = (bf16*)(ws + 86 * MB);    // [86,102M) gated mem
    bf16* UPD   = (bf16*)(ws + 102 * MB);   // [102,118M) updated mem
    bf16* WCOMB = (bf16*)(ws + 118 * MB);   // [118,124M) (3072x1024)
    bf16* WOGB  = (bf16*)(ws + 124 * MB);   // [124,126M)
    bf16* WFGB  = (bf16*)(ws + 126 * MB);   // [126,130M) (1024x2048)
    bf16* WVB   = (bf16*)(ws + 130 * MB);   // [130,132M)
    bf16* WOPB  = (bf16*)(ws + 132 * MB);   // [132,134M)
    bf16* WIHB  = (bf16*)(ws + 134 * MB);   // [134,140M) (3072x1024)
    bf16* WIPT  = (bf16*)(ws + 140 * MB);   // [140,142M)
    bf16* T1T   = (bf16*)(ws + 142 * MB);   // [142,144M)
    bf16* T2T   = (bf16*)(ws + 144 * MB);   // [144,146M)
    float* T1B  = (float*)(ws + 146 * MB);
    float* T2B  = (float*)(ws + 146 * MB + 8192);
    float* T3B  = (float*)(ws + 146 * MB + 16384);  // 3072 f32

    const int M = B_ROWS;
    dim3 blk(256);

    // L1: prep (cat, 6 casts, Wip^T, ones) + gemv1
    prep_k<<<dim3(28936), blk, 0, stream>>>(
        prev, input, CAT,
        in_proj_w + 2048 * 1024, out_proj_w, gih_w, fg_w, og_w, ghh_w,
        WVB, WOPB, WIHB, WFGB, WOGB, WHHB,
        ip_w, WIPT, out + (size_t)M * 1024,
        ip_b, in_proj_b + 2048, T1B);
    // L2: T1T = (Wv@Wip)^T  +  T2B = Wop@T1B+bop  +  fg -> GATED
    comb1_k<<<dim3(640), blk, 0, stream>>>(
        WVB, WIPT, T1T,
        out_proj_w, T1B, out_proj_b, T2B,
        CAT, WFGB, fg_b, prev, GATED);
    // L3: T2T = (Wop@..)^T  +  T3B = Wih@T2B+bih
    comb2_k<<<dim3(896), blk, 0, stream>>>(
        WOPB, T1T, T2T,
        gih_w, T2B, gih_b, T3B);
    // L4: Wcomb = Wih @ T2T^T  [3072,1024]
    gemm64_k<<<dim3(384), blk, 0, stream>>>(WIHB, T2T, WCOMB);
    // L5: Grz (two-phase K) + gi_n
    big_k<<<dim3(768), blk, 0, stream>>>(
        CAT + 1024, WCOMB, GATED, WHHB, T3B, ghh_b, GRZ,
        WCOMB + (size_t)2048 * 1024, T3B + 2048, GNI);
    // L6: gh_n + fused GRU combine -> UPD
    g3_k<<<dim3(256), blk, 0, stream>>>(
        GATED, WHHB + (size_t)2048 * 1024, ghh_b + 2048, GRZ, GNI, UPD);
    // L7: out = upd * sigmoid(upd @ Wog^T + bog)
    og_k<<<dim3(256), blk, 0, stream>>>(UPD, WOGB, og_b, out);
}